// Round 3
// baseline (62077.850 us; speedup 1.0000x reference)
//
#include <hip/hip_runtime.h>
#include <math.h>

// Problem constants (from reference)
#define Bsz   32
#define Lmem  512
#define Tsteps 400
#define EMBD  512
#define PRE   256
#define ENCD  512
#define ARNN  1024
#define DRNN  1024
#define NSYM  256
// MEAN_COEFF = 1.0f, SCALE_COEFF = 10.0f

typedef _Float16 f16x8 __attribute__((ext_vector_type(8)));
typedef float    f32x4 __attribute__((ext_vector_type(4)));
typedef _Float16 half_t;

// ---------------------------------------------------------------------------
// Weight conversion/packing (one-time): Wcat = [Wih | Whh] rows in f16,
// bsum = bih + bhh.
// ---------------------------------------------------------------------------
template<int KIH, int KHH>
__global__ __launch_bounds__(256) void conv_lstm_w(
    const float* __restrict__ Wih, const float* __restrict__ Whh,
    const float* __restrict__ bih, const float* __restrict__ bhh,
    half_t* __restrict__ Wcat, float* __restrict__ bsum)
{
    constexpr int K = KIH + KHH;
    const int j = blockIdx.x;
    const float* srcA = Wih + (size_t)j * KIH;
    const float* srcB = Whh + (size_t)j * KHH;
    half_t* dst = Wcat + (size_t)j * K;
    for (int k = threadIdx.x; k < KIH; k += 256) dst[k]       = (half_t)srcA[k];
    for (int k = threadIdx.x; k < KHH; k += 256) dst[KIH + k] = (half_t)srcB[k];
    if (threadIdx.x == 0) bsum[j] = bih[j] + bhh[j];
}

__global__ __launch_bounds__(256) void conv_mat(
    const float* __restrict__ src, half_t* __restrict__ dst, int n)
{
    for (int i = blockIdx.x * 256 + threadIdx.x; i < n; i += gridDim.x * 256)
        dst[i] = (half_t)src[i];
}

// ---------------------------------------------------------------------------
// Prenet (parallel over all T*B rows, one-time): f16 output (T,B,PRE)
// ---------------------------------------------------------------------------
__global__ __launch_bounds__(256) void prenet_kernel(
    const float* __restrict__ din,   // (B, EMB, T)
    const float* __restrict__ pW1, const float* __restrict__ pb1,
    const float* __restrict__ pW2, const float* __restrict__ pb2,
    half_t* __restrict__ xpre)       // (T, B, PRE) f16
{
    __shared__ float xs[8][EMBD];
    __shared__ float h1s[8][PRE];
    const int tid = threadIdx.x;
    const int row0 = blockIdx.x * 8;

    for (int idx = tid; idx < 8 * EMBD; idx += 256) {
        int r = idx >> 9;
        int e = idx & 511;
        int rid = row0 + r;
        int t = rid >> 5;
        int b = rid & 31;
        float v = 0.f;
        if (t > 0) v = din[(size_t)b * EMBD * Tsteps + (size_t)e * Tsteps + (t - 1)];
        xs[r][e] = v;
    }
    __syncthreads();

    {
        float acc[8] = {0.f,0.f,0.f,0.f,0.f,0.f,0.f,0.f};
        const float* wr = pW1 + (size_t)tid * EMBD;
        for (int e = 0; e < EMBD; e += 4) {
            float4 wv = *(const float4*)(wr + e);
            #pragma unroll
            for (int r = 0; r < 8; ++r) {
                float4 xv = *(const float4*)&xs[r][e];
                acc[r] += wv.x * xv.x + wv.y * xv.y + wv.z * xv.z + wv.w * xv.w;
            }
        }
        float bias = pb1[tid];
        #pragma unroll
        for (int r = 0; r < 8; ++r) h1s[r][tid] = fmaxf(acc[r] + bias, 0.f);
    }
    __syncthreads();

    {
        float acc[8] = {0.f,0.f,0.f,0.f,0.f,0.f,0.f,0.f};
        const float* wr = pW2 + (size_t)tid * PRE;
        for (int e = 0; e < PRE; e += 4) {
            float4 wv = *(const float4*)(wr + e);
            #pragma unroll
            for (int r = 0; r < 8; ++r) {
                float4 xv = *(const float4*)&h1s[r][e];
                acc[r] += wv.x * xv.x + wv.y * xv.y + wv.z * xv.z + wv.w * xv.w;
            }
        }
        float bias = pb2[tid];
        #pragma unroll
        for (int r = 0; r < 8; ++r) {
            int rid = row0 + r;
            int t = rid >> 5;
            int b = rid & 31;
            xpre[(size_t)t * Bsz * PRE + (size_t)b * PRE + tid] =
                (half_t)fmaxf(acc[r] + bias, 0.f);
        }
    }
}

// ---------------------------------------------------------------------------
// Device-wide barrier for the persistent kernel (256 co-resident blocks).
// Agent-scope atomics + threadfence handle cross-XCD L2 non-coherence.
// ---------------------------------------------------------------------------
__device__ __forceinline__ void gsync(unsigned* cnt, unsigned* gen)
{
    __syncthreads();
    if (threadIdx.x == 0) {
        __threadfence();   // release this block's phase writes (L2 writeback)
        unsigned g = __hip_atomic_load(gen, __ATOMIC_RELAXED, __HIP_MEMORY_SCOPE_AGENT);
        unsigned a = __hip_atomic_fetch_add(cnt, 1u, __ATOMIC_ACQ_REL, __HIP_MEMORY_SCOPE_AGENT);
        if (a == 255u) {
            __hip_atomic_store(cnt, 0u, __ATOMIC_RELAXED, __HIP_MEMORY_SCOPE_AGENT);
            __hip_atomic_store(gen, g + 1u, __ATOMIC_RELEASE, __HIP_MEMORY_SCOPE_AGENT);
        } else {
            while (__hip_atomic_load(gen, __ATOMIC_ACQUIRE, __HIP_MEMORY_SCOPE_AGENT) == g)
                __builtin_amdgcn_s_sleep(2);
        }
        __threadfence();   // acquire: invalidate stale lines before next phase
    }
    __syncthreads();
}

// ---------------------------------------------------------------------------
// Persistent decoder kernel. 256 blocks x 512 threads (1 block/CU).
// Block = 4 units x 4 gates (16 W-rows) x 32 batches for both LSTMs;
// waves: btile = w&1, kq = w>>1 (K quarter). LSTM weights held in VGPRs
// for the whole T loop (wA 56 + wD 80 regs/thread).
// Per step: PHASE A (aLSTM + out_{t-1}) | bar | PHASE B (attention) | bar |
//           PHASE C (dLSTM) | bar.
// ---------------------------------------------------------------------------
__global__ __launch_bounds__(512, 1) void decoder_persistent(
    const half_t* __restrict__ Wcat_a, const float* __restrict__ bsum_a,
    const half_t* __restrict__ Wcat_d, const float* __restrict__ bsum_d,
    const half_t* __restrict__ Wo, const float* __restrict__ ob,
    const half_t* __restrict__ xpre,
    const float* __restrict__ attWp, const float* __restrict__ attbp,
    const int* __restrict__ mlen, const float* __restrict__ memory,
    float* __restrict__ ac, float* __restrict__ dc,
    half_t* __restrict__ ah0, half_t* __restrict__ ah1,
    half_t* __restrict__ dh0, half_t* __restrict__ dh1,
    half_t* __restrict__ ctx,
    float* __restrict__ mean0, float* __restrict__ mean1,
    float* __restrict__ logits, float* __restrict__ aligns,
    float* __restrict__ ps,
    unsigned* cnt, unsigned* gen)
{
    const int blk   = blockIdx.x;
    const int tid   = threadIdx.x;
    const int wave  = tid >> 6;
    const int lane  = tid & 63;
    const int btile = wave & 1;
    const int kq    = wave >> 1;
    const int m15   = lane & 15;
    const int kh    = lane >> 4;
    const int u0    = blk << 2;
    const int jrow  = (m15 >> 2) * 1024 + u0 + (m15 & 3);
    const int bb    = (btile << 4) + m15;    // batch column for B-frag

    constexpr int KA = PRE + ENCD + ARNN;    // 1792
    constexpr int KAQ = KA / 4;              // 448
    constexpr int NMA = KAQ / 32;            // 14
    constexpr int KD = ARNN + ENCD + DRNN;   // 2560
    constexpr int KDQ = KD / 4;              // 640
    constexpr int NMD = KDQ / 32;            // 20

    // ---- hoist LSTM weights into registers (persist across the T loop) ----
    f16x8 wA[NMA], wD[NMD];
    {
        const half_t* ar = Wcat_a + (size_t)jrow * KA + kq * KAQ + (kh << 3);
        #pragma unroll
        for (int i = 0; i < NMA; ++i) wA[i] = *(const f16x8*)(ar + i * 32);
        const half_t* dr = Wcat_d + (size_t)jrow * KD + kq * KDQ + (kh << 3);
        #pragma unroll
        for (int i = 0; i < NMD; ++i) wD[i] = *(const f16x8*)(dr + i * 32);
    }
    // cached epilogue biases (threads 0..127 only)
    float bsA[4] = {0.f,0.f,0.f,0.f}, bsD[4] = {0.f,0.f,0.f,0.f};
    if (tid < 128) {
        const int ul = tid >> 5;
        #pragma unroll
        for (int gi = 0; gi < 4; ++gi) {
            bsA[gi] = bsum_a[gi * 1024 + u0 + ul];
            bsD[gi] = bsum_d[gi * 1024 + u0 + ul];
        }
    }

    __shared__ float gred[4][2][16][16];   // 8 KB, reused by both LSTMs
    __shared__ float lred[16][33];         // out-projection reduce
    __shared__ float wsh[Lmem];
    __shared__ float red[8][64];
    __shared__ float wred8[8][2];
    __shared__ float bc2[2];

    for (int t = 0; t < Tsteps; ++t) {
        const half_t* ah_in  = (t & 1) ? ah1 : ah0;
        half_t*       ah_out = (t & 1) ? ah0 : ah1;
        const half_t* dh_in  = (t & 1) ? dh1 : dh0;
        half_t*       dh_out = (t & 1) ? dh0 : dh1;
        const float*  mn_in  = (t & 1) ? mean1 : mean0;
        float*        mn_out = (t & 1) ? mean0 : mean1;

        // ================= PHASE A: aLSTM  (+ out projection for t-1) ======
        {
            const half_t* s0 = xpre + (size_t)t * Bsz * PRE;
            f32x4 acc = {0.f, 0.f, 0.f, 0.f};
            const int kbase = kq * KAQ;
            #pragma unroll
            for (int i = 0; i < NMA; ++i) {
                const int kg = kbase + i * 32 + (kh << 3);
                const half_t* bp = (kg < PRE)        ? (s0 + bb * PRE + kg)
                                 : (kg < PRE + ENCD) ? (ctx + bb * ENCD + (kg - PRE))
                                                     : (ah_in + bb * ARNN + (kg - PRE - ENCD));
                f16x8 bv = *(const f16x8*)bp;
                acc = __builtin_amdgcn_mfma_f32_16x16x32_f16(wA[i], bv, acc, 0, 0, 0);
            }
            #pragma unroll
            for (int r = 0; r < 4; ++r)
                gred[kq][btile][(kh << 2) + r][m15] = acc[r];
        }
        // out projection partial for step t-1 (row n = blk), reads dh_{t-1}, ctx_{t-1}
        {
            const int b_o = tid & 31;
            const int ks  = tid >> 5;          // 0..15
            const half_t* wrow = Wo + (size_t)blk * (DRNN + ENCD) + ks * 96;
            float outacc = 0.f;
            #pragma unroll
            for (int kk = 0; kk < 96; kk += 8) {
                const int k = ks * 96 + kk;
                f16x8 wv = *(const f16x8*)(wrow + kk);
                const half_t* ap = (k < DRNN) ? (dh_in + b_o * DRNN + k)
                                              : (ctx + b_o * ENCD + (k - DRNN));
                f16x8 av = *(const f16x8*)ap;
                #pragma unroll
                for (int e = 0; e < 8; ++e)
                    outacc += (float)wv[e] * (float)av[e];
            }
            lred[ks][b_o] = outacc;
        }
        __syncthreads();
        // aLSTM cell update
        if (tid < 128) {
            const int ul = tid >> 5;
            const int bq = tid & 31;
            const int bt = bq >> 4;
            const int nn = bq & 15;
            float g[4];
            #pragma unroll
            for (int gi = 0; gi < 4; ++gi) {
                const int mr = (gi << 2) + ul;
                g[gi] = gred[0][bt][mr][nn] + gred[1][bt][mr][nn]
                      + gred[2][bt][mr][nn] + gred[3][bt][mr][nn] + bsA[gi];
            }
            const int idx = bq * 1024 + u0 + ul;
            float co = ac[idx];
            float si = 1.f / (1.f + expf(-g[0]));
            float sf = 1.f / (1.f + expf(-g[1]));
            float so = 1.f / (1.f + expf(-g[3]));
            float cn = sf * co + si * tanhf(g[2]);
            ac[idx] = cn;
            ah_out[idx] = (half_t)(so * tanhf(cn));
        }
        // out projection reduce + store (t-1)
        if (t > 0 && tid < 32) {
            float s = 0.f;
            #pragma unroll
            for (int q = 0; q < 16; ++q) s += lred[q][tid];
            logits[(size_t)tid * Tsteps * NSYM + (size_t)(t - 1) * NSYM + blk] =
                s + ob[blk];
        }
        gsync(cnt, gen);

        // ================= PHASE B: attention ===============================
        {
            const int abt = blk >> 3;   // batch
            const int dt  = blk & 7;    // d-tile
            float p0 = 0.f, p1 = 0.f;
            for (int k = tid; k < ARNN; k += 512) {
                float a = (float)ah_out[abt * ARNN + k];
                p0 += a * attWp[k];
                p1 += a * attWp[ARNN + k];
            }
            #pragma unroll
            for (int off = 32; off > 0; off >>= 1) {
                p0 += __shfl_down(p0, off, 64);
                p1 += __shfl_down(p1, off, 64);
            }
            if (lane == 0) { wred8[wave][0] = p0; wred8[wave][1] = p1; }
            __syncthreads();
            if (tid == 0) {
                float q0 = attbp[0], q1 = attbp[1];
                #pragma unroll
                for (int w = 0; w < 8; ++w) { q0 += wred8[w][0]; q1 += wred8[w][1]; }
                float mn = mn_in[abt] + expf(q0) * 1.0f;   // MEAN_COEFF
                float sc = expf(q1) * 10.0f;               // SCALE_COEFF
                if (dt == 0) {
                    mn_out[abt] = mn;
                    ps[(size_t)abt * Tsteps * 2 + (size_t)t * 2 + 0] = q0;
                    ps[(size_t)abt * Tsteps * 2 + (size_t)t * 2 + 1] = q1;
                }
                bc2[0] = mn; bc2[1] = sc;
            }
            __syncthreads();
            const float mn = bc2[0], sc = bc2[1];
            const float inv_s = 1.f / sc;
            const float coef = 0.3989422804014327f * inv_s;
            const int len = mlen[abt];
            {
                float z = ((float)tid - mn) * inv_s;
                float wv = (tid < len) ? expf(-0.5f * z * z) * coef : 0.f;
                wsh[tid] = wv;
                if (dt == 0)
                    aligns[(size_t)abt * Tsteps * Lmem + (size_t)t * Lmem + tid] = wv;
            }
            __syncthreads();
            // ctx over +-9 sigma window (w < 1e-19 outside)
            int lo = (int)fmaxf(0.f, floorf(mn - 9.f * sc));
            int hi = (int)fminf((float)len, ceilf(mn + 9.f * sc) + 1.f);
            const int d  = (dt << 6) + (tid & 63);
            const int lq = tid >> 6;
            const float* mb = memory + (size_t)abt * Lmem * ENCD + d;
            float acc = 0.f;
            for (int l = lo + lq; l < hi; l += 8)
                acc += wsh[l] * mb[(size_t)l * ENCD];
            red[lq][tid & 63] = acc;
            __syncthreads();
            if (tid < 64) {
                float s = 0.f;
                #pragma unroll
                for (int q = 0; q < 8; ++q) s += red[q][tid];
                ctx[abt * ENCD + (dt << 6) + tid] = (half_t)s;
            }
        }
        gsync(cnt, gen);

        // ================= PHASE C: dLSTM ===================================
        {
            f32x4 acc = {0.f, 0.f, 0.f, 0.f};
            const int kbase = kq * KDQ;
            #pragma unroll
            for (int i = 0; i < NMD; ++i) {
                const int kg = kbase + i * 32 + (kh << 3);
                const half_t* bp = (kg < ARNN)        ? (ah_out + bb * ARNN + kg)
                                 : (kg < ARNN + ENCD) ? (ctx + bb * ENCD + (kg - ARNN))
                                                      : (dh_in + bb * DRNN + (kg - ARNN - ENCD));
                f16x8 bv = *(const f16x8*)bp;
                acc = __builtin_amdgcn_mfma_f32_16x16x32_f16(wD[i], bv, acc, 0, 0, 0);
            }
            #pragma unroll
            for (int r = 0; r < 4; ++r)
                gred[kq][btile][(kh << 2) + r][m15] = acc[r];
        }
        __syncthreads();
        if (tid < 128) {
            const int ul = tid >> 5;
            const int bq = tid & 31;
            const int bt = bq >> 4;
            const int nn = bq & 15;
            float g[4];
            #pragma unroll
            for (int gi = 0; gi < 4; ++gi) {
                const int mr = (gi << 2) + ul;
                g[gi] = gred[0][bt][mr][nn] + gred[1][bt][mr][nn]
                      + gred[2][bt][mr][nn] + gred[3][bt][mr][nn] + bsD[gi];
            }
            const int idx = bq * 1024 + u0 + ul;
            float co = dc[idx];
            float si = 1.f / (1.f + expf(-g[0]));
            float sf = 1.f / (1.f + expf(-g[1]));
            float so = 1.f / (1.f + expf(-g[3]));
            float cn = sf * co + si * tanhf(g[2]);
            dc[idx] = cn;
            dh_out[idx] = (half_t)(so * tanhf(cn));
        }
        gsync(cnt, gen);
    }

    // ================= final out projection (t = Tsteps-1) =================
    {
        const half_t* dhF = ((Tsteps - 1) & 1) ? dh0 : dh1;   // dh_out of last step
        const int b_o = tid & 31;
        const int ks  = tid >> 5;
        const half_t* wrow = Wo + (size_t)blk * (DRNN + ENCD) + ks * 96;
        float outacc = 0.f;
        #pragma unroll
        for (int kk = 0; kk < 96; kk += 8) {
            const int k = ks * 96 + kk;
            f16x8 wv = *(const f16x8*)(wrow + kk);
            const half_t* ap = (k < DRNN) ? (dhF + b_o * DRNN + k)
                                          : (ctx + b_o * ENCD + (k - DRNN));
            f16x8 av = *(const f16x8*)ap;
            #pragma unroll
            for (int e = 0; e < 8; ++e)
                outacc += (float)wv[e] * (float)av[e];
        }
        lred[ks][b_o] = outacc;
        __syncthreads();
        if (tid < 32) {
            float s = 0.f;
            #pragma unroll
            for (int q = 0; q < 16; ++q) s += lred[q][tid];
            logits[(size_t)tid * Tsteps * NSYM + (size_t)(Tsteps - 1) * NSYM + blk] =
                s + ob[blk];
        }
    }
}

// ---------------------------------------------------------------------------
extern "C" void kernel_launch(void* const* d_in, const int* in_sizes, int n_in,
                              void* d_out, int out_size, void* d_ws, size_t ws_size,
                              hipStream_t stream)
{
    (void)in_sizes; (void)n_in; (void)out_size; (void)ws_size;
    const float* memory = (const float*)d_in[0];
    const float* din    = (const float*)d_in[1];
    const int*   mlen   = (const int*)d_in[2];
    const float* pW1    = (const float*)d_in[3];
    const float* pb1    = (const float*)d_in[4];
    const float* pW2    = (const float*)d_in[5];
    const float* pb2    = (const float*)d_in[6];
    const float* aWih   = (const float*)d_in[7];
    const float* aWhh   = (const float*)d_in[8];
    const float* abih   = (const float*)d_in[9];
    const float* abhh   = (const float*)d_in[10];
    const float* attWp  = (const float*)d_in[11];
    const float* attbp  = (const float*)d_in[12];
    const float* dWih   = (const float*)d_in[13];
    const float* dWhh   = (const float*)d_in[14];
    const float* dbih   = (const float*)d_in[15];
    const float* dbhh   = (const float*)d_in[16];
    const float* oW     = (const float*)d_in[17];
    const float* ob     = (const float*)d_in[18];

    float* logits = (float*)d_out;                                  // B*T*NSYM
    float* aligns = logits + (size_t)Bsz * Tsteps * NSYM;           // B*T*L
    float* ps     = aligns + (size_t)Bsz * Tsteps * Lmem;           // B*T*2

    char* base = (char*)d_ws;
    auto alloc = [&](size_t bytes) -> char* {
        char* p = base; base += (bytes + 255) & ~(size_t)255; return p;
    };
    half_t* Wcat_a = (half_t*)alloc((size_t)4096 * 1792 * 2);
    half_t* Wcat_d = (half_t*)alloc((size_t)4096 * 2560 * 2);
    half_t* Wo     = (half_t*)alloc((size_t)NSYM * (DRNN + ENCD) * 2);
    float*  bsum_a = (float*)alloc(4096 * 4);
    float*  bsum_d = (float*)alloc(4096 * 4);
    half_t* xpre   = (half_t*)alloc((size_t)Tsteps * Bsz * PRE * 2);
    half_t* ah0    = (half_t*)alloc(Bsz * ARNN * 2);
    half_t* ah1    = (half_t*)alloc(Bsz * ARNN * 2);
    half_t* dh0    = (half_t*)alloc(Bsz * DRNN * 2);
    half_t* dh1    = (half_t*)alloc(Bsz * DRNN * 2);
    half_t* ctx    = (half_t*)alloc(Bsz * ENCD * 2);
    float*  ac     = (float*)alloc(Bsz * ARNN * 4);
    float*  dc     = (float*)alloc(Bsz * DRNN * 4);
    float*  mean0  = (float*)alloc(Bsz * 4);
    float*  mean1  = (float*)alloc(Bsz * 4);
    unsigned* bar  = (unsigned*)alloc(256);    // cnt @ [0], gen @ [32]

    // zero-init recurrent state + barrier vars (every call; graph-safe)
    hipMemsetAsync(ah0,   0, Bsz * ARNN * 2, stream);
    hipMemsetAsync(dh0,   0, Bsz * DRNN * 2, stream);
    hipMemsetAsync(ctx,   0, Bsz * ENCD * 2, stream);
    hipMemsetAsync(ac,    0, Bsz * ARNN * 4, stream);
    hipMemsetAsync(dc,    0, Bsz * DRNN * 4, stream);
    hipMemsetAsync(mean0, 0, Bsz * 4, stream);
    hipMemsetAsync(bar,   0, 256, stream);

    // one-time weight conversion + prenet
    conv_lstm_w<PRE + ENCD, ARNN><<<4096, 256, 0, stream>>>(
        aWih, aWhh, abih, abhh, Wcat_a, bsum_a);
    conv_lstm_w<ARNN + ENCD, DRNN><<<4096, 256, 0, stream>>>(
        dWih, dWhh, dbih, dbhh, Wcat_d, bsum_d);
    conv_mat<<<768, 256, 0, stream>>>(oW, Wo, NSYM * (DRNN + ENCD));
    prenet_kernel<<<Tsteps * Bsz / 8, 256, 0, stream>>>(din, pW1, pb1, pW2, pb2, xpre);

    // the whole T=400 recurrence in one persistent kernel
    decoder_persistent<<<256, 512, 0, stream>>>(
        Wcat_a, bsum_a, Wcat_d, bsum_d, Wo, ob, xpre,
        attWp, attbp, mlen, memory,
        ac, dc, ah0, ah1, dh0, dh1, ctx, mean0, mean1,
        logits, aligns, ps,
        bar + 0, bar + 8);
}

// Round 4
// 40819.571 us; speedup vs baseline: 1.5208x; 1.5208x over previous
//
#include <hip/hip_runtime.h>
#include <math.h>

// Problem constants (from reference)
#define Bsz   32
#define Lmem  512
#define Tsteps 400
#define EMBD  512
#define PRE   256
#define ENCD  512
#define ARNN  1024
#define DRNN  1024
#define NSYM  256
// MEAN_COEFF = 1.0f, SCALE_COEFF = 10.0f

typedef _Float16 f16x8 __attribute__((ext_vector_type(8)));
typedef float    f32x4 __attribute__((ext_vector_type(4)));
typedef _Float16 half_t;

#define KA  (PRE + ENCD + ARNN)    // 1792
#define KAQ (KA / 4)               // 448
#define NMA (KAQ / 32)             // 14
#define KD  (ARNN + ENCD + DRNN)   // 2560
#define KDQ (KD / 4)               // 640
#define NMD (KDQ / 32)             // 20
#define LDA_A 1800                 // KA + 8 pad  (900 dw = 4 mod 32 -> conflict-free b128)
#define LDA_D 2568                 // KD + 8 pad  (1284 dw = 4 mod 32)

// ---------------------------------------------------------------------------
// Weight conversion/packing (one-time): Wcat = [Wih | Whh] rows in f16,
// bsum = bih + bhh.
// ---------------------------------------------------------------------------
template<int KIH, int KHH>
__global__ __launch_bounds__(256) void conv_lstm_w(
    const float* __restrict__ Wih, const float* __restrict__ Whh,
    const float* __restrict__ bih, const float* __restrict__ bhh,
    half_t* __restrict__ Wcat, float* __restrict__ bsum)
{
    constexpr int K = KIH + KHH;
    const int j = blockIdx.x;
    const float* srcA = Wih + (size_t)j * KIH;
    const float* srcB = Whh + (size_t)j * KHH;
    half_t* dst = Wcat + (size_t)j * K;
    for (int k = threadIdx.x; k < KIH; k += 256) dst[k]       = (half_t)srcA[k];
    for (int k = threadIdx.x; k < KHH; k += 256) dst[KIH + k] = (half_t)srcB[k];
    if (threadIdx.x == 0) bsum[j] = bih[j] + bhh[j];
}

__global__ __launch_bounds__(256) void conv_mat(
    const float* __restrict__ src, half_t* __restrict__ dst, int n)
{
    for (int i = blockIdx.x * 256 + threadIdx.x; i < n; i += gridDim.x * 256)
        dst[i] = (half_t)src[i];
}

// ---------------------------------------------------------------------------
// Prenet (parallel over all T*B rows, one-time): f16 output (T,B,PRE)
// ---------------------------------------------------------------------------
__global__ __launch_bounds__(256) void prenet_kernel(
    const float* __restrict__ din,   // (B, EMB, T)
    const float* __restrict__ pW1, const float* __restrict__ pb1,
    const float* __restrict__ pW2, const float* __restrict__ pb2,
    half_t* __restrict__ xpre)       // (T, B, PRE) f16
{
    __shared__ float xs[8][EMBD];
    __shared__ float h1s[8][PRE];
    const int tid = threadIdx.x;
    const int row0 = blockIdx.x * 8;

    for (int idx = tid; idx < 8 * EMBD; idx += 256) {
        int r = idx >> 9;
        int e = idx & 511;
        int rid = row0 + r;
        int t = rid >> 5;
        int b = rid & 31;
        float v = 0.f;
        if (t > 0) v = din[(size_t)b * EMBD * Tsteps + (size_t)e * Tsteps + (t - 1)];
        xs[r][e] = v;
    }
    __syncthreads();

    {
        float acc[8] = {0.f,0.f,0.f,0.f,0.f,0.f,0.f,0.f};
        const float* wr = pW1 + (size_t)tid * EMBD;
        for (int e = 0; e < EMBD; e += 4) {
            float4 wv = *(const float4*)(wr + e);
            #pragma unroll
            for (int r = 0; r < 8; ++r) {
                float4 xv = *(const float4*)&xs[r][e];
                acc[r] += wv.x * xv.x + wv.y * xv.y + wv.z * xv.z + wv.w * xv.w;
            }
        }
        float bias = pb1[tid];
        #pragma unroll
        for (int r = 0; r < 8; ++r) h1s[r][tid] = fmaxf(acc[r] + bias, 0.f);
    }
    __syncthreads();

    {
        float acc[8] = {0.f,0.f,0.f,0.f,0.f,0.f,0.f,0.f};
        const float* wr = pW2 + (size_t)tid * PRE;
        for (int e = 0; e < PRE; e += 4) {
            float4 wv = *(const float4*)(wr + e);
            #pragma unroll
            for (int r = 0; r < 8; ++r) {
                float4 xv = *(const float4*)&h1s[r][e];
                acc[r] += wv.x * xv.x + wv.y * xv.y + wv.z * xv.z + wv.w * xv.w;
            }
        }
        float bias = pb2[tid];
        #pragma unroll
        for (int r = 0; r < 8; ++r) {
            int rid = row0 + r;
            int t = rid >> 5;
            int b = rid & 31;
            xpre[(size_t)t * Bsz * PRE + (size_t)b * PRE + tid] =
                (half_t)fmaxf(acc[r] + bias, 0.f);
        }
    }
}

// ---------------------------------------------------------------------------
// RMW-free hierarchical device barrier (256 co-resident blocks).
// Arrival: each block release-STOREs its own padded flag (parallel, no RMW).
// Block 0: threads 0..255 poll one flag each in parallel, then publish gen.
// All blocks: tid0 spins on gen (single line, read-only).
// ph is monotonically increasing (no reset races).
// ---------------------------------------------------------------------------
__device__ __forceinline__ void gsync(unsigned* flags, unsigned* gen, unsigned ph)
{
    __syncthreads();
    if (threadIdx.x == 0) {
        __threadfence();   // make this block's phase writes device-visible
        __hip_atomic_store(flags + blockIdx.x * 16, ph,
                           __ATOMIC_RELEASE, __HIP_MEMORY_SCOPE_AGENT);
    }
    if (blockIdx.x == 0) {
        if (threadIdx.x < 256) {
            while (__hip_atomic_load(flags + threadIdx.x * 16,
                                     __ATOMIC_ACQUIRE, __HIP_MEMORY_SCOPE_AGENT) < ph)
                __builtin_amdgcn_s_sleep(1);
        }
        __syncthreads();
        if (threadIdx.x == 0)
            __hip_atomic_store(gen, ph, __ATOMIC_RELEASE, __HIP_MEMORY_SCOPE_AGENT);
    }
    if (threadIdx.x == 0) {
        while (__hip_atomic_load(gen, __ATOMIC_ACQUIRE, __HIP_MEMORY_SCOPE_AGENT) < ph)
            __builtin_amdgcn_s_sleep(1);
        __threadfence();   // acquire: discard stale lines before next phase
    }
    __syncthreads();
}

// ---------------------------------------------------------------------------
// Persistent decoder. 256 blocks x 512 threads (1 block/CU). LSTM weights for
// this block's 16 rows live in LDS for the whole T loop (150 KB of 160 KB).
// Software-pipelined, 2 barriers/step over T+1 iterations:
//   phase1: aLSTM_t  || dLSTM_{t-1}          (independent)
//   phase2: att_t    || outproj_{t-1}        (independent)
// ah/dh/ctx/mean double-buffered by step parity; c-states block-owned.
// ---------------------------------------------------------------------------
__global__ __launch_bounds__(512, 1) void decoder_persistent(
    const half_t* __restrict__ Wcat_a, const float* __restrict__ bsum_a,
    const half_t* __restrict__ Wcat_d, const float* __restrict__ bsum_d,
    const half_t* __restrict__ Wo, const float* __restrict__ ob,
    const half_t* __restrict__ xpre,
    const float* __restrict__ attWp, const float* __restrict__ attbp,
    const int* __restrict__ mlen, const half_t* __restrict__ mem16,
    float* __restrict__ ac, float* __restrict__ dc,
    half_t* __restrict__ ah0, half_t* __restrict__ ah1,
    half_t* __restrict__ dh0, half_t* __restrict__ dh1,
    half_t* __restrict__ ctx0, half_t* __restrict__ ctx1,
    float* __restrict__ mean0, float* __restrict__ mean1,
    float* __restrict__ logits, float* __restrict__ aligns,
    float* __restrict__ ps,
    unsigned* flags, unsigned* gen)
{
    const int blk   = blockIdx.x;
    const int tid   = threadIdx.x;
    const int wave  = tid >> 6;
    const int lane  = tid & 63;
    const int btile = wave & 1;
    const int kq    = wave >> 1;
    const int m15   = lane & 15;
    const int kh    = lane >> 4;
    const int u0    = blk << 2;
    const int bb    = (btile << 4) + m15;    // batch column for B-frag

    __shared__ __align__(16) half_t wAl[16 * LDA_A];   // 57.6 KB
    __shared__ __align__(16) half_t wDl[16 * LDA_D];   // 82.2 KB
    __shared__ float gred[4][2][16][16];               // 8 KB
    __shared__ float wsh[Lmem];                        // 2 KB
    __shared__ float red[8][64];                       // 2 KB
    __shared__ float lred[16][33];                     // 2.1 KB
    __shared__ float wred8[8][2];
    __shared__ float bc2[2];

    // ---- stage this block's weight rows into LDS (one-time) ----
    for (int g = tid; g < 16 * (KA / 8); g += 512) {
        int r = g / (KA / 8);
        int c = (g - r * (KA / 8)) * 8;
        int jr = (r >> 2) * 1024 + u0 + (r & 3);
        *(f16x8*)(wAl + r * LDA_A + c) = *(const f16x8*)(Wcat_a + (size_t)jr * KA + c);
    }
    for (int g = tid; g < 16 * (KD / 8); g += 512) {
        int r = g / (KD / 8);
        int c = (g - r * (KD / 8)) * 8;
        int jr = (r >> 2) * 1024 + u0 + (r & 3);
        *(f16x8*)(wDl + r * LDA_D + c) = *(const f16x8*)(Wcat_d + (size_t)jr * KD + c);
    }
    // epilogue biases (threads 0..127)
    float bsA[4] = {0.f,0.f,0.f,0.f}, bsD[4] = {0.f,0.f,0.f,0.f};
    if (tid < 128) {
        const int ul = tid >> 5;
        #pragma unroll
        for (int gi = 0; gi < 4; ++gi) {
            bsA[gi] = bsum_a[gi * 1024 + u0 + ul];
            bsD[gi] = bsum_d[gi * 1024 + u0 + ul];
        }
    }
    const half_t* lA = wAl + m15 * LDA_A + kq * KAQ + (kh << 3);
    const half_t* lD = wDl + m15 * LDA_D + kq * KDQ + (kh << 3);
    __syncthreads();

    unsigned ph = 0;

    for (int t = 0; t <= Tsteps; ++t) {
        const int par = t & 1;
        half_t*       ah_cur  = par ? ah1 : ah0;     // ah_t
        const half_t* ah_prv  = par ? ah0 : ah1;     // ah_{t-1}
        half_t*       ctx_cur = par ? ctx1 : ctx0;   // ctx_t
        const half_t* ctx_prv = par ? ctx0 : ctx1;   // ctx_{t-1}
        float*        mn_cur  = par ? mean1 : mean0;
        const float*  mn_prv  = par ? mean0 : mean1;
        half_t*       dh_s    = par ? dh0 : dh1;     // dh_{t-1} (written)
        const half_t* dh_prv  = par ? dh1 : dh0;     // dh_{t-2}

        // ================= PHASE 1: aLSTM_t || dLSTM_{t-1} =================
        f32x4 accA = {0.f,0.f,0.f,0.f};
        f32x4 accD = {0.f,0.f,0.f,0.f};
        if (t < Tsteps) {
            const half_t* s0 = xpre + (size_t)t * Bsz * PRE;
            #pragma unroll
            for (int i = 0; i < NMA; ++i) {
                f16x8 av = *(const f16x8*)(lA + i * 32);
                const int kg = kq * KAQ + i * 32 + (kh << 3);
                const half_t* bp = (kg < PRE)        ? (s0 + bb * PRE + kg)
                                 : (kg < PRE + ENCD) ? (ctx_prv + bb * ENCD + (kg - PRE))
                                                     : (ah_prv + bb * ARNN + (kg - PRE - ENCD));
                f16x8 bv = *(const f16x8*)bp;
                accA = __builtin_amdgcn_mfma_f32_16x16x32_f16(av, bv, accA, 0, 0, 0);
            }
        }
        if (t > 0) {
            #pragma unroll
            for (int i = 0; i < NMD; ++i) {
                f16x8 av = *(const f16x8*)(lD + i * 32);
                const int kg = kq * KDQ + i * 32 + (kh << 3);
                const half_t* bp = (kg < ARNN)        ? (ah_prv + bb * ARNN + kg)
                                 : (kg < ARNN + ENCD) ? (ctx_prv + bb * ENCD + (kg - ARNN))
                                                      : (dh_prv + bb * DRNN + (kg - ARNN - ENCD));
                f16x8 bv = *(const f16x8*)bp;
                accD = __builtin_amdgcn_mfma_f32_16x16x32_f16(av, bv, accD, 0, 0, 0);
            }
        }
        if (t < Tsteps) {
            #pragma unroll
            for (int r = 0; r < 4; ++r)
                gred[kq][btile][(kh << 2) + r][m15] = accA[r];
            __syncthreads();
            if (tid < 128) {
                const int ul = tid >> 5;
                const int bq = tid & 31;
                const int bt = bq >> 4;
                const int nn = bq & 15;
                float g[4];
                #pragma unroll
                for (int gi = 0; gi < 4; ++gi) {
                    const int mr = (gi << 2) + ul;
                    g[gi] = gred[0][bt][mr][nn] + gred[1][bt][mr][nn]
                          + gred[2][bt][mr][nn] + gred[3][bt][mr][nn] + bsA[gi];
                }
                const int idx = bq * 1024 + u0 + ul;
                float co = ac[idx];
                float si = 1.f / (1.f + expf(-g[0]));
                float sf = 1.f / (1.f + expf(-g[1]));
                float so = 1.f / (1.f + expf(-g[3]));
                float cn = sf * co + si * tanhf(g[2]);
                ac[idx] = cn;
                ah_cur[idx] = (half_t)(so * tanhf(cn));
            }
            __syncthreads();
        }
        if (t > 0) {
            #pragma unroll
            for (int r = 0; r < 4; ++r)
                gred[kq][btile][(kh << 2) + r][m15] = accD[r];
            __syncthreads();
            if (tid < 128) {
                const int ul = tid >> 5;
                const int bq = tid & 31;
                const int bt = bq >> 4;
                const int nn = bq & 15;
                float g[4];
                #pragma unroll
                for (int gi = 0; gi < 4; ++gi) {
                    const int mr = (gi << 2) + ul;
                    g[gi] = gred[0][bt][mr][nn] + gred[1][bt][mr][nn]
                          + gred[2][bt][mr][nn] + gred[3][bt][mr][nn] + bsD[gi];
                }
                const int idx = bq * 1024 + u0 + ul;
                float co = dc[idx];
                float si = 1.f / (1.f + expf(-g[0]));
                float sf = 1.f / (1.f + expf(-g[1]));
                float so = 1.f / (1.f + expf(-g[3]));
                float cn = sf * co + si * tanhf(g[2]);
                dc[idx] = cn;
                dh_s[idx] = (half_t)(so * tanhf(cn));
            }
        }
        ++ph; gsync(flags, gen, ph);

        // ================= PHASE 2: att_t || outproj_{t-1} =================
        if (t < Tsteps) {
            const int abt = blk >> 3;   // batch
            const int dt  = blk & 7;    // d-tile
            float p0 = 0.f, p1 = 0.f;
            for (int k = tid; k < ARNN; k += 512) {
                float a = (float)ah_cur[abt * ARNN + k];
                p0 += a * attWp[k];
                p1 += a * attWp[ARNN + k];
            }
            #pragma unroll
            for (int off = 32; off > 0; off >>= 1) {
                p0 += __shfl_down(p0, off, 64);
                p1 += __shfl_down(p1, off, 64);
            }
            if (lane == 0) { wred8[wave][0] = p0; wred8[wave][1] = p1; }
            __syncthreads();
            if (tid == 0) {
                float q0 = attbp[0], q1 = attbp[1];
                #pragma unroll
                for (int w = 0; w < 8; ++w) { q0 += wred8[w][0]; q1 += wred8[w][1]; }
                float mn = mn_prv[abt] + expf(q0) * 1.0f;   // MEAN_COEFF
                float sc = expf(q1) * 10.0f;                // SCALE_COEFF
                if (dt == 0) {
                    mn_cur[abt] = mn;
                    ps[(size_t)abt * Tsteps * 2 + (size_t)t * 2 + 0] = q0;
                    ps[(size_t)abt * Tsteps * 2 + (size_t)t * 2 + 1] = q1;
                }
                bc2[0] = mn; bc2[1] = sc;
            }
            __syncthreads();
            const float mn = bc2[0], sc = bc2[1];
            const float inv_s = 1.f / sc;
            const float coef = 0.3989422804014327f * inv_s;
            const int len = mlen[abt];
            {
                float z = ((float)tid - mn) * inv_s;
                float wv = (tid < len) ? expf(-0.5f * z * z) * coef : 0.f;
                wsh[tid] = wv;
                if (dt == 0)
                    aligns[(size_t)abt * Tsteps * Lmem + (size_t)t * Lmem + tid] = wv;
            }
            __syncthreads();
            // ctx over +-9 sigma window (w < 1e-19 outside)
            int lo = (int)fmaxf(0.f, floorf(mn - 9.f * sc));
            int hi = (int)fminf((float)len, ceilf(mn + 9.f * sc) + 1.f);
            const int d  = (dt << 6) + (tid & 63);
            const int lq = tid >> 6;
            const half_t* mb = mem16 + (size_t)abt * Lmem * ENCD + d;
            float acc = 0.f;
            for (int l = lo + lq; l < hi; l += 8)
                acc += wsh[l] * (float)mb[(size_t)l * ENCD];
            red[lq][tid & 63] = acc;
            __syncthreads();
            if (tid < 64) {
                float s = 0.f;
                #pragma unroll
                for (int q = 0; q < 8; ++q) s += red[q][tid];
                ctx_cur[abt * ENCD + (dt << 6) + tid] = (half_t)s;
            }
        }
        if (t > 0) {
            // output projection for step t-1: row n = blk, all 32 batches
            const int b_o = tid & 31;
            const int ks  = tid >> 5;          // 0..15
            const half_t* wrow = Wo + (size_t)blk * (DRNN + ENCD) + ks * 96;
            float outacc = 0.f;
            #pragma unroll
            for (int kk = 0; kk < 96; kk += 8) {
                const int k = ks * 96 + kk;
                f16x8 wv = *(const f16x8*)(wrow + kk);
                const half_t* ap = (k < DRNN) ? (dh_s + b_o * DRNN + k)
                                              : (ctx_prv + b_o * ENCD + (k - DRNN));
                f16x8 av = *(const f16x8*)ap;
                #pragma unroll
                for (int e = 0; e < 8; ++e)
                    outacc += (float)wv[e] * (float)av[e];
            }
            lred[ks][b_o] = outacc;
            __syncthreads();
            if (tid < 32) {
                float s = 0.f;
                #pragma unroll
                for (int q = 0; q < 16; ++q) s += lred[q][tid];
                logits[(size_t)tid * Tsteps * NSYM + (size_t)(t - 1) * NSYM + blk] =
                    s + ob[blk];
            }
        }
        if (t < Tsteps) { ++ph; gsync(flags, gen, ph); }
    }
}

// ---------------------------------------------------------------------------
extern "C" void kernel_launch(void* const* d_in, const int* in_sizes, int n_in,
                              void* d_out, int out_size, void* d_ws, size_t ws_size,
                              hipStream_t stream)
{
    (void)in_sizes; (void)n_in; (void)out_size; (void)ws_size;
    const float* memory = (const float*)d_in[0];
    const float* din    = (const float*)d_in[1];
    const int*   mlen   = (const int*)d_in[2];
    const float* pW1    = (const float*)d_in[3];
    const float* pb1    = (const float*)d_in[4];
    const float* pW2    = (const float*)d_in[5];
    const float* pb2    = (const float*)d_in[6];
    const float* aWih   = (const float*)d_in[7];
    const float* aWhh   = (const float*)d_in[8];
    const float* abih   = (const float*)d_in[9];
    const float* abhh   = (const float*)d_in[10];
    const float* attWp  = (const float*)d_in[11];
    const float* attbp  = (const float*)d_in[12];
    const float* dWih   = (const float*)d_in[13];
    const float* dWhh   = (const float*)d_in[14];
    const float* dbih   = (const float*)d_in[15];
    const float* dbhh   = (const float*)d_in[16];
    const float* oW     = (const float*)d_in[17];
    const float* ob     = (const float*)d_in[18];

    float* logits = (float*)d_out;                                  // B*T*NSYM
    float* aligns = logits + (size_t)Bsz * Tsteps * NSYM;           // B*T*L
    float* ps     = aligns + (size_t)Bsz * Tsteps * Lmem;           // B*T*2

    char* base = (char*)d_ws;
    auto alloc = [&](size_t bytes) -> char* {
        char* p = base; base += (bytes + 255) & ~(size_t)255; return p;
    };
    half_t* Wcat_a = (half_t*)alloc((size_t)4096 * KA * 2);
    half_t* Wcat_d = (half_t*)alloc((size_t)4096 * KD * 2);
    half_t* Wo     = (half_t*)alloc((size_t)NSYM * (DRNN + ENCD) * 2);
    float*  bsum_a = (float*)alloc(4096 * 4);
    float*  bsum_d = (float*)alloc(4096 * 4);
    half_t* xpre   = (half_t*)alloc((size_t)Tsteps * Bsz * PRE * 2);
    half_t* mem16  = (half_t*)alloc((size_t)Bsz * Lmem * ENCD * 2);
    half_t* ah0    = (half_t*)alloc(Bsz * ARNN * 2);
    half_t* ah1    = (half_t*)alloc(Bsz * ARNN * 2);
    half_t* dh0    = (half_t*)alloc(Bsz * DRNN * 2);
    half_t* dh1    = (half_t*)alloc(Bsz * DRNN * 2);
    half_t* ctx0   = (half_t*)alloc(Bsz * ENCD * 2);
    half_t* ctx1   = (half_t*)alloc(Bsz * ENCD * 2);
    float*  ac     = (float*)alloc(Bsz * ARNN * 4);
    float*  dc     = (float*)alloc(Bsz * DRNN * 4);
    float*  mean0  = (float*)alloc(Bsz * 4);
    float*  mean1  = (float*)alloc(Bsz * 4);
    unsigned* flags = (unsigned*)alloc(256 * 16 * 4);   // padded arrival flags
    unsigned* gen   = (unsigned*)alloc(256);

    // zero-init recurrent state + barrier vars (every call; graph-safe)
    hipMemsetAsync(ah1,   0, Bsz * ARNN * 2, stream);
    hipMemsetAsync(dh1,   0, Bsz * DRNN * 2, stream);
    hipMemsetAsync(ctx1,  0, Bsz * ENCD * 2, stream);
    hipMemsetAsync(ac,    0, Bsz * ARNN * 4, stream);
    hipMemsetAsync(dc,    0, Bsz * DRNN * 4, stream);
    hipMemsetAsync(mean0, 0, Bsz * 4, stream);
    hipMemsetAsync(mean1, 0, Bsz * 4, stream);
    hipMemsetAsync(flags, 0, 256 * 16 * 4, stream);
    hipMemsetAsync(gen,   0, 256, stream);

    // one-time weight conversion + prenet + memory->f16
    conv_lstm_w<PRE + ENCD, ARNN><<<4096, 256, 0, stream>>>(
        aWih, aWhh, abih, abhh, Wcat_a, bsum_a);
    conv_lstm_w<ARNN + ENCD, DRNN><<<4096, 256, 0, stream>>>(
        dWih, dWhh, dbih, dbhh, Wcat_d, bsum_d);
    conv_mat<<<768, 256, 0, stream>>>(oW, Wo, NSYM * (DRNN + ENCD));
    conv_mat<<<4096, 256, 0, stream>>>(memory, mem16, Bsz * Lmem * ENCD);
    prenet_kernel<<<Tsteps * Bsz / 8, 256, 0, stream>>>(din, pW1, pb1, pW2, pb2, xpre);

    // the whole T=400 recurrence in one persistent kernel
    decoder_persistent<<<256, 512, 0, stream>>>(
        Wcat_a, bsum_a, Wcat_d, bsum_d, Wo, ob, xpre,
        attWp, attbp, mlen, mem16,
        ac, dc, ah0, ah1, dh0, dh1, ctx0, ctx1, mean0, mean1,
        logits, aligns, ps,
        flags, gen);
}

// Round 6
// 19494.568 us; speedup vs baseline: 3.1844x; 2.0939x over previous
//
#include <hip/hip_runtime.h>
#include <math.h>

// Problem constants (from reference)
#define Bsz   32
#define Lmem  512
#define Tsteps 400
#define EMBD  512
#define PRE   256
#define ENCD  512
#define ARNN  1024
#define DRNN  1024
#define NSYM  256
// MEAN_COEFF = 1.0f, SCALE_COEFF = 10.0f

typedef _Float16 f16x8 __attribute__((ext_vector_type(8)));
typedef float    f32x4 __attribute__((ext_vector_type(4)));
typedef _Float16 half_t;

#define KA  (PRE + ENCD + ARNN)    // 1792
#define KAQ (KA / 4)               // 448
#define NMA (KAQ / 32)             // 14
#define KD  (ARNN + ENCD + DRNN)   // 2560
#define KDQ (KD / 4)               // 640
#define NMD (KDQ / 32)             // 20
#define LDA_A 1800                 // KA + 8 pad  (900 dw = 4 mod 32 -> conflict-free b128)
#define LDA_D 2568                 // KD + 8 pad  (1284 dw = 4 mod 32)

// ---- agent-scope (cross-XCD coherent) scalar access helpers ---------------
// Relaxed atomic ops at AGENT scope emit global_load/store with sc1:
// write-through past the non-coherent per-XCD L2, read from the coherence
// point. No wbl2/inv in these (that's the point).
__device__ __forceinline__ void st_agent_f16(half_t* p, half_t v) {
    __hip_atomic_store((unsigned short*)p, __builtin_bit_cast(unsigned short, v),
                       __ATOMIC_RELAXED, __HIP_MEMORY_SCOPE_AGENT);
}
__device__ __forceinline__ void st_agent_f32(float* p, float v) {
    __hip_atomic_store(p, v, __ATOMIC_RELAXED, __HIP_MEMORY_SCOPE_AGENT);
}

// ---------------------------------------------------------------------------
// Weight conversion/packing (one-time): Wcat = [Wih | Whh] rows in f16,
// bsum = bih + bhh.
// ---------------------------------------------------------------------------
template<int KIH, int KHH>
__global__ __launch_bounds__(256) void conv_lstm_w(
    const float* __restrict__ Wih, const float* __restrict__ Whh,
    const float* __restrict__ bih, const float* __restrict__ bhh,
    half_t* __restrict__ Wcat, float* __restrict__ bsum)
{
    constexpr int K = KIH + KHH;
    const int j = blockIdx.x;
    const float* srcA = Wih + (size_t)j * KIH;
    const float* srcB = Whh + (size_t)j * KHH;
    half_t* dst = Wcat + (size_t)j * K;
    for (int k = threadIdx.x; k < KIH; k += 256) dst[k]       = (half_t)srcA[k];
    for (int k = threadIdx.x; k < KHH; k += 256) dst[KIH + k] = (half_t)srcB[k];
    if (threadIdx.x == 0) bsum[j] = bih[j] + bhh[j];
}

__global__ __launch_bounds__(256) void conv_mat(
    const float* __restrict__ src, half_t* __restrict__ dst, int n)
{
    for (int i = blockIdx.x * 256 + threadIdx.x; i < n; i += gridDim.x * 256)
        dst[i] = (half_t)src[i];
}

// ---------------------------------------------------------------------------
// Prenet (parallel over all T*B rows, one-time): f16 output (T,B,PRE)
// ---------------------------------------------------------------------------
__global__ __launch_bounds__(256) void prenet_kernel(
    const float* __restrict__ din,   // (B, EMB, T)
    const float* __restrict__ pW1, const float* __restrict__ pb1,
    const float* __restrict__ pW2, const float* __restrict__ pb2,
    half_t* __restrict__ xpre)       // (T, B, PRE) f16
{
    __shared__ float xs[8][EMBD];
    __shared__ float h1s[8][PRE];
    const int tid = threadIdx.x;
    const int row0 = blockIdx.x * 8;

    for (int idx = tid; idx < 8 * EMBD; idx += 256) {
        int r = idx >> 9;
        int e = idx & 511;
        int rid = row0 + r;
        int t = rid >> 5;
        int b = rid & 31;
        float v = 0.f;
        if (t > 0) v = din[(size_t)b * EMBD * Tsteps + (size_t)e * Tsteps + (t - 1)];
        xs[r][e] = v;
    }
    __syncthreads();

    {
        float acc[8] = {0.f,0.f,0.f,0.f,0.f,0.f,0.f,0.f};
        const float* wr = pW1 + (size_t)tid * EMBD;
        for (int e = 0; e < EMBD; e += 4) {
            float4 wv = *(const float4*)(wr + e);
            #pragma unroll
            for (int r = 0; r < 8; ++r) {
                float4 xv = *(const float4*)&xs[r][e];
                acc[r] += wv.x * xv.x + wv.y * xv.y + wv.z * xv.z + wv.w * xv.w;
            }
        }
        float bias = pb1[tid];
        #pragma unroll
        for (int r = 0; r < 8; ++r) h1s[r][tid] = fmaxf(acc[r] + bias, 0.f);
    }
    __syncthreads();

    {
        float acc[8] = {0.f,0.f,0.f,0.f,0.f,0.f,0.f,0.f};
        const float* wr = pW2 + (size_t)tid * PRE;
        for (int e = 0; e < PRE; e += 4) {
            float4 wv = *(const float4*)(wr + e);
            #pragma unroll
            for (int r = 0; r < 8; ++r) {
                float4 xv = *(const float4*)&h1s[r][e];
                acc[r] += wv.x * xv.x + wv.y * xv.y + wv.z * xv.z + wv.w * xv.w;
            }
        }
        float bias = pb2[tid];
        #pragma unroll
        for (int r = 0; r < 8; ++r) {
            int rid = row0 + r;
            int t = rid >> 5;
            int b = rid & 31;
            xpre[(size_t)t * Bsz * PRE + (size_t)b * PRE + tid] =
                (half_t)fmaxf(acc[r] + bias, 0.f);
        }
    }
}

// ---------------------------------------------------------------------------
// Symmetric RMW-free device barrier (256 co-resident blocks).
// All communicated data is written sc1 (write-through) -> no wbl2 needed.
// Arrival: per-wave vmcnt drain + block barrier, then tid0 relaxed-stores the
// block's padded flag. Threads 0..255 poll one flag each with RELAXED sc1
// loads (no cache invalidates in the loop). Exactly ONE acquire fence
// (buffer_inv) per block per barrier, after the poll. ph is monotone.
// ---------------------------------------------------------------------------
__device__ __forceinline__ void gsync(unsigned* flags, unsigned ph)
{
    asm volatile("s_waitcnt vmcnt(0)" ::: "memory");   // this wave's stores done
    __syncthreads();                                   // all waves arrived
    if (threadIdx.x == 0)
        __hip_atomic_store(flags + blockIdx.x * 16, ph,
                           __ATOMIC_RELAXED, __HIP_MEMORY_SCOPE_AGENT);
    if (threadIdx.x < 256) {
        while (__hip_atomic_load(flags + threadIdx.x * 16,
                                 __ATOMIC_RELAXED, __HIP_MEMORY_SCOPE_AGENT) < ph)
            __builtin_amdgcn_s_sleep(8);
    }
    __builtin_amdgcn_fence(__ATOMIC_ACQUIRE, "agent");  // one buffer_inv
    __syncthreads();
}

// ---------------------------------------------------------------------------
// Persistent decoder. 256 blocks x 512 threads (1 block/CU). LSTM weights for
// this block's 16 rows live in LDS for the whole T loop (150 KB of 160 KB).
// c-states live in REGISTERS (block-private). Software-pipelined,
// 2 barriers/step over T+1 iterations:
//   phase1: aLSTM_t  || dLSTM_{t-1}          (independent)
//   phase2: att_t    || outproj_{t-1}        (independent)
// ah/dh/ctx/mean double-buffered by step parity; all cross-block stores sc1.
// ---------------------------------------------------------------------------
__global__ __launch_bounds__(512, 1) void decoder_persistent(
    const half_t* __restrict__ Wcat_a, const float* __restrict__ bsum_a,
    const half_t* __restrict__ Wcat_d, const float* __restrict__ bsum_d,
    const half_t* __restrict__ Wo, const float* __restrict__ ob,
    const half_t* __restrict__ xpre,
    const float* __restrict__ attWp, const float* __restrict__ attbp,
    const int* __restrict__ mlen, const half_t* __restrict__ mem16,
    half_t* __restrict__ ah0, half_t* __restrict__ ah1,
    half_t* __restrict__ dh0, half_t* __restrict__ dh1,
    half_t* __restrict__ ctx0, half_t* __restrict__ ctx1,
    float* __restrict__ mean0, float* __restrict__ mean1,
    float* __restrict__ logits, float* __restrict__ aligns,
    float* __restrict__ ps,
    unsigned* flags)
{
    const int blk   = blockIdx.x;
    const int tid   = threadIdx.x;
    const int wave  = tid >> 6;
    const int lane  = tid & 63;
    const int btile = wave & 1;
    const int kq    = wave >> 1;
    const int m15   = lane & 15;
    const int kh    = lane >> 4;
    const int u0    = blk << 2;
    const int bb    = (btile << 4) + m15;    // batch column for B-frag

    __shared__ __align__(16) half_t wAl[16 * LDA_A];   // 57.6 KB
    __shared__ __align__(16) half_t wDl[16 * LDA_D];   // 82.2 KB
    __shared__ float gred[4][2][16][16];               // 8 KB
    __shared__ float wsh[Lmem];                        // 2 KB
    __shared__ float red[8][64];                       // 2 KB
    __shared__ float lred[16][33];                     // 2.1 KB
    __shared__ float wred8[8][2];
    __shared__ float bc2[2];

    // ---- stage this block's weight rows into LDS (one-time) ----
    for (int g = tid; g < 16 * (KA / 8); g += 512) {
        int r = g / (KA / 8);
        int c = (g - r * (KA / 8)) * 8;
        int jr = (r >> 2) * 1024 + u0 + (r & 3);
        *(f16x8*)(wAl + r * LDA_A + c) = *(const f16x8*)(Wcat_a + (size_t)jr * KA + c);
    }
    for (int g = tid; g < 16 * (KD / 8); g += 512) {
        int r = g / (KD / 8);
        int c = (g - r * (KD / 8)) * 8;
        int jr = (r >> 2) * 1024 + u0 + (r & 3);
        *(f16x8*)(wDl + r * LDA_D + c) = *(const f16x8*)(Wcat_d + (size_t)jr * KD + c);
    }
    // epilogue biases (threads 0..127) + register-resident c-states
    float bsA[4] = {0.f,0.f,0.f,0.f}, bsD[4] = {0.f,0.f,0.f,0.f};
    float cA = 0.f, cD = 0.f;
    if (tid < 128) {
        const int ul = tid >> 5;
        #pragma unroll
        for (int gi = 0; gi < 4; ++gi) {
            bsA[gi] = bsum_a[gi * 1024 + u0 + ul];
            bsD[gi] = bsum_d[gi * 1024 + u0 + ul];
        }
    }
    const half_t* lA = wAl + m15 * LDA_A + kq * KAQ + (kh << 3);
    const half_t* lD = wDl + m15 * LDA_D + kq * KDQ + (kh << 3);
    __syncthreads();

    unsigned ph = 0;

    for (int t = 0; t <= Tsteps; ++t) {
        const int par = t & 1;
        half_t*       ah_cur  = par ? ah1 : ah0;     // ah_t
        const half_t* ah_prv  = par ? ah0 : ah1;     // ah_{t-1}
        half_t*       ctx_cur = par ? ctx1 : ctx0;   // ctx_t
        const half_t* ctx_prv = par ? ctx0 : ctx1;   // ctx_{t-1}
        float*        mn_cur  = par ? mean1 : mean0;
        const float*  mn_prv  = par ? mean0 : mean1;
        half_t*       dh_s    = par ? dh0 : dh1;     // dh_{t-1} (written)
        const half_t* dh_prv  = par ? dh1 : dh0;     // dh_{t-2}

        // ================= PHASE 1: aLSTM_t || dLSTM_{t-1} =================
        f32x4 accA = {0.f,0.f,0.f,0.f};
        f32x4 accD = {0.f,0.f,0.f,0.f};
        if (t < Tsteps) {
            const half_t* s0 = xpre + (size_t)t * Bsz * PRE;
            #pragma unroll
            for (int i = 0; i < NMA; ++i) {
                f16x8 av = *(const f16x8*)(lA + i * 32);
                const int kg = kq * KAQ + i * 32 + (kh << 3);
                const half_t* bp = (kg < PRE)        ? (s0 + bb * PRE + kg)
                                 : (kg < PRE + ENCD) ? (ctx_prv + bb * ENCD + (kg - PRE))
                                                     : (ah_prv + bb * ARNN + (kg - PRE - ENCD));
                f16x8 bv = *(const f16x8*)bp;
                accA = __builtin_amdgcn_mfma_f32_16x16x32_f16(av, bv, accA, 0, 0, 0);
            }
        }
        if (t > 0) {
            #pragma unroll
            for (int i = 0; i < NMD; ++i) {
                f16x8 av = *(const f16x8*)(lD + i * 32);
                const int kg = kq * KDQ + i * 32 + (kh << 3);
                const half_t* bp = (kg < ARNN)        ? (ah_prv + bb * ARNN + kg)
                                 : (kg < ARNN + ENCD) ? (ctx_prv + bb * ENCD + (kg - ARNN))
                                                      : (dh_prv + bb * DRNN + (kg - ARNN - ENCD));
                f16x8 bv = *(const f16x8*)bp;
                accD = __builtin_amdgcn_mfma_f32_16x16x32_f16(av, bv, accD, 0, 0, 0);
            }
        }
        if (t < Tsteps) {
            #pragma unroll
            for (int r = 0; r < 4; ++r)
                gred[kq][btile][(kh << 2) + r][m15] = accA[r];
            __syncthreads();
            if (tid < 128) {
                const int ul = tid >> 5;
                const int bq = tid & 31;
                const int bt = bq >> 4;
                const int nn = bq & 15;
                float g[4];
                #pragma unroll
                for (int gi = 0; gi < 4; ++gi) {
                    const int mr = (gi << 2) + ul;
                    g[gi] = gred[0][bt][mr][nn] + gred[1][bt][mr][nn]
                          + gred[2][bt][mr][nn] + gred[3][bt][mr][nn] + bsA[gi];
                }
                float si = 1.f / (1.f + expf(-g[0]));
                float sf = 1.f / (1.f + expf(-g[1]));
                float so = 1.f / (1.f + expf(-g[3]));
                cA = sf * cA + si * tanhf(g[2]);
                st_agent_f16(&ah_cur[bq * 1024 + u0 + ul], (half_t)(so * tanhf(cA)));
            }
            __syncthreads();
        }
        if (t > 0) {
            #pragma unroll
            for (int r = 0; r < 4; ++r)
                gred[kq][btile][(kh << 2) + r][m15] = accD[r];
            __syncthreads();
            if (tid < 128) {
                const int ul = tid >> 5;
                const int bq = tid & 31;
                const int bt = bq >> 4;
                const int nn = bq & 15;
                float g[4];
                #pragma unroll
                for (int gi = 0; gi < 4; ++gi) {
                    const int mr = (gi << 2) + ul;
                    g[gi] = gred[0][bt][mr][nn] + gred[1][bt][mr][nn]
                          + gred[2][bt][mr][nn] + gred[3][bt][mr][nn] + bsD[gi];
                }
                float si = 1.f / (1.f + expf(-g[0]));
                float sf = 1.f / (1.f + expf(-g[1]));
                float so = 1.f / (1.f + expf(-g[3]));
                cD = sf * cD + si * tanhf(g[2]);
                st_agent_f16(&dh_s[bq * 1024 + u0 + ul], (half_t)(so * tanhf(cD)));
            }
        }
        ++ph; gsync(flags, ph);

        // ================= PHASE 2: att_t || outproj_{t-1} =================
        if (t < Tsteps) {
            const int abt = blk >> 3;   // batch
            const int dt  = blk & 7;    // d-tile
            float p0 = 0.f, p1 = 0.f;
            for (int k = tid; k < ARNN; k += 512) {
                float a = (float)ah_cur[abt * ARNN + k];
                p0 += a * attWp[k];
                p1 += a * attWp[ARNN + k];
            }
            #pragma unroll
            for (int off = 32; off > 0; off >>= 1) {
                p0 += __shfl_down(p0, off, 64);
                p1 += __shfl_down(p1, off, 64);
            }
            if (lane == 0) { wred8[wave][0] = p0; wred8[wave][1] = p1; }
            __syncthreads();
            if (tid == 0) {
                float q0 = attbp[0], q1 = attbp[1];
                #pragma unroll
                for (int w = 0; w < 8; ++w) { q0 += wred8[w][0]; q1 += wred8[w][1]; }
                float mn = mn_prv[abt] + expf(q0) * 1.0f;   // MEAN_COEFF
                float sc = expf(q1) * 10.0f;                // SCALE_COEFF
                if (dt == 0) {
                    st_agent_f32(&mn_cur[abt], mn);
                    st_agent_f32(&ps[(size_t)abt * Tsteps * 2 + (size_t)t * 2 + 0], q0);
                    st_agent_f32(&ps[(size_t)abt * Tsteps * 2 + (size_t)t * 2 + 1], q1);
                }
                bc2[0] = mn; bc2[1] = sc;
            }
            __syncthreads();
            const float mn = bc2[0], sc = bc2[1];
            const float inv_s = 1.f / sc;
            const float coef = 0.3989422804014327f * inv_s;
            const int len = mlen[abt];
            {
                float z = ((float)tid - mn) * inv_s;
                float wv = (tid < len) ? expf(-0.5f * z * z) * coef : 0.f;
                wsh[tid] = wv;
                if (dt == 0)
                    st_agent_f32(&aligns[(size_t)abt * Tsteps * Lmem + (size_t)t * Lmem + tid], wv);
            }
            __syncthreads();
            // ctx over +-9 sigma window (w < 1e-19 outside)
            int lo = (int)fmaxf(0.f, floorf(mn - 9.f * sc));
            int hi = (int)fminf((float)len, ceilf(mn + 9.f * sc) + 1.f);
            const int d  = (dt << 6) + (tid & 63);
            const int lq = tid >> 6;
            const half_t* mb = mem16 + (size_t)abt * Lmem * ENCD + d;
            float acc = 0.f;
            for (int l = lo + lq; l < hi; l += 8)
                acc += wsh[l] * (float)mb[(size_t)l * ENCD];
            red[lq][tid & 63] = acc;
            __syncthreads();
            if (tid < 64) {
                float s = 0.f;
                #pragma unroll
                for (int q = 0; q < 8; ++q) s += red[q][tid];
                st_agent_f16(&ctx_cur[abt * ENCD + (dt << 6) + tid], (half_t)s);
            }
        }
        if (t > 0) {
            // output projection for step t-1: row n = blk, all 32 batches
            const int b_o = tid & 31;
            const int ks  = tid >> 5;          // 0..15
            const half_t* wrow = Wo + (size_t)blk * (DRNN + ENCD) + ks * 96;
            float outacc = 0.f;
            #pragma unroll
            for (int kk = 0; kk < 96; kk += 8) {
                const int k = ks * 96 + kk;
                f16x8 wv = *(const f16x8*)(wrow + kk);
                const half_t* ap = (k < DRNN) ? (dh_s + b_o * DRNN + k)
                                              : (ctx_prv + b_o * ENCD + (k - DRNN));
                f16x8 av = *(const f16x8*)ap;
                #pragma unroll
                for (int e = 0; e < 8; ++e)
                    outacc += (float)wv[e] * (float)av[e];
            }
            lred[ks][b_o] = outacc;
            __syncthreads();
            if (tid < 32) {
                float s = 0.f;
                #pragma unroll
                for (int q = 0; q < 16; ++q) s += lred[q][tid];
                st_agent_f32(&logits[(size_t)tid * Tsteps * NSYM + (size_t)(t - 1) * NSYM + blk],
                             s + ob[blk]);
            }
        }
        if (t < Tsteps) { ++ph; gsync(flags, ph); }
    }
}

// ---------------------------------------------------------------------------
extern "C" void kernel_launch(void* const* d_in, const int* in_sizes, int n_in,
                              void* d_out, int out_size, void* d_ws, size_t ws_size,
                              hipStream_t stream)
{
    (void)in_sizes; (void)n_in; (void)out_size; (void)ws_size;
    const float* memory = (const float*)d_in[0];
    const float* din    = (const float*)d_in[1];
    const int*   mlen   = (const int*)d_in[2];
    const float* pW1    = (const float*)d_in[3];
    const float* pb1    = (const float*)d_in[4];
    const float* pW2    = (const float*)d_in[5];
    const float* pb2    = (const float*)d_in[6];
    const float* aWih   = (const float*)d_in[7];
    const float* aWhh   = (const float*)d_in[8];
    const float* abih   = (const float*)d_in[9];
    const float* abhh   = (const float*)d_in[10];
    const float* attWp  = (const float*)d_in[11];
    const float* attbp  = (const float*)d_in[12];
    const float* dWih   = (const float*)d_in[13];
    const float* dWhh   = (const float*)d_in[14];
    const float* dbih   = (const float*)d_in[15];
    const float* dbhh   = (const float*)d_in[16];
    const float* oW     = (const float*)d_in[17];
    const float* ob     = (const float*)d_in[18];

    float* logits = (float*)d_out;                                  // B*T*NSYM
    float* aligns = logits + (size_t)Bsz * Tsteps * NSYM;           // B*T*L
    float* ps     = aligns + (size_t)Bsz * Tsteps * Lmem;           // B*T*2

    char* base = (char*)d_ws;
    auto alloc = [&](size_t bytes) -> char* {
        char* p = base; base += (bytes + 255) & ~(size_t)255; return p;
    };
    half_t* Wcat_a = (half_t*)alloc((size_t)4096 * KA * 2);
    half_t* Wcat_d = (half_t*)alloc((size_t)4096 * KD * 2);
    half_t* Wo     = (half_t*)alloc((size_t)NSYM * (DRNN + ENCD) * 2);
    float*  bsum_a = (float*)alloc(4096 * 4);
    float*  bsum_d = (float*)alloc(4096 * 4);
    half_t* xpre   = (half_t*)alloc((size_t)Tsteps * Bsz * PRE * 2);
    half_t* mem16  = (half_t*)alloc((size_t)Bsz * Lmem * ENCD * 2);
    half_t* ah0    = (half_t*)alloc(Bsz * ARNN * 2);
    half_t* ah1    = (half_t*)alloc(Bsz * ARNN * 2);
    half_t* dh0    = (half_t*)alloc(Bsz * DRNN * 2);
    half_t* dh1    = (half_t*)alloc(Bsz * DRNN * 2);
    half_t* ctx0   = (half_t*)alloc(Bsz * ENCD * 2);
    half_t* ctx1   = (half_t*)alloc(Bsz * ENCD * 2);
    float*  mean0  = (float*)alloc(Bsz * 4);
    float*  mean1  = (float*)alloc(Bsz * 4);
    unsigned* flags = (unsigned*)alloc(256 * 16 * 4);   // padded arrival flags

    // zero-init recurrent state + barrier flags (every call; graph-safe)
    (void)hipMemsetAsync(ah1,   0, Bsz * ARNN * 2, stream);
    (void)hipMemsetAsync(dh1,   0, Bsz * DRNN * 2, stream);
    (void)hipMemsetAsync(ctx1,  0, Bsz * ENCD * 2, stream);
    (void)hipMemsetAsync(mean0, 0, Bsz * 4, stream);
    (void)hipMemsetAsync(mean1, 0, Bsz * 4, stream);
    (void)hipMemsetAsync(flags, 0, 256 * 16 * 4, stream);

    // one-time weight conversion + prenet + memory->f16
    conv_lstm_w<PRE + ENCD, ARNN><<<4096, 256, 0, stream>>>(
        aWih, aWhh, abih, abhh, Wcat_a, bsum_a);
    conv_lstm_w<ARNN + ENCD, DRNN><<<4096, 256, 0, stream>>>(
        dWih, dWhh, dbih, dbhh, Wcat_d, bsum_d);
    conv_mat<<<768, 256, 0, stream>>>(oW, Wo, NSYM * (DRNN + ENCD));
    conv_mat<<<4096, 256, 0, stream>>>(memory, mem16, Bsz * Lmem * ENCD);
    prenet_kernel<<<Tsteps * Bsz / 8, 256, 0, stream>>>(din, pW1, pb1, pW2, pb2, xpre);

    // the whole T=400 recurrence in one persistent kernel
    decoder_persistent<<<256, 512, 0, stream>>>(
        Wcat_a, bsum_a, Wcat_d, bsum_d, Wo, ob, xpre,
        attWp, attbp, mlen, mem16,
        ah0, ah1, dh0, dh1, ctx0, ctx1, mean0, mean1,
        logits, aligns, ps,
        flags);
}

// Round 7
// 16259.253 us; speedup vs baseline: 3.8180x; 1.1990x over previous
//
#include <hip/hip_runtime.h>
#include <math.h>

// Problem constants (from reference)
#define Bsz   32
#define Lmem  512
#define Tsteps 400
#define EMBD  512
#define PRE   256
#define ENCD  512
#define ARNN  1024
#define DRNN  1024
#define NSYM  256
// MEAN_COEFF = 1.0f, SCALE_COEFF = 10.0f

typedef _Float16 f16x8 __attribute__((ext_vector_type(8)));
typedef float    f32x4 __attribute__((ext_vector_type(4)));
typedef _Float16 half_t;

#define KA  (PRE + ENCD + ARNN)    // 1792
#define KAQ (KA / 4)               // 448
#define NMA (KAQ / 32)             // 14
#define KD  (ARNN + ENCD + DRNN)   // 2560
#define KDQ (KD / 4)               // 640
#define NMD (KDQ / 32)             // 20
#define LDA_A 1800                 // KA + 8 pad
#define LDA_D 2568                 // KD + 8 pad

// ---- agent-scope (cross-XCD) access helpers: sc1 loads/stores bypass the
// non-coherent per-XCD L2; read-only data uses PLAIN loads and stays L2-hot.
// No cache-invalidate fences anywhere.
__device__ __forceinline__ void st_agent_f16(half_t* p, half_t v) {
    __hip_atomic_store((unsigned short*)p, __builtin_bit_cast(unsigned short, v),
                       __ATOMIC_RELAXED, __HIP_MEMORY_SCOPE_AGENT);
}
__device__ __forceinline__ void st_agent_f32(float* p, float v) {
    __hip_atomic_store(p, v, __ATOMIC_RELAXED, __HIP_MEMORY_SCOPE_AGENT);
}
__device__ __forceinline__ void st_agent_u32(unsigned* p, unsigned v) {
    __hip_atomic_store(p, v, __ATOMIC_RELAXED, __HIP_MEMORY_SCOPE_AGENT);
}
__device__ __forceinline__ float ld_agent_f32(const float* p) {
    return __hip_atomic_load(p, __ATOMIC_RELAXED, __HIP_MEMORY_SCOPE_AGENT);
}
__device__ __forceinline__ unsigned ld_agent_u32(const unsigned* p) {
    return __hip_atomic_load(p, __ATOMIC_RELAXED, __HIP_MEMORY_SCOPE_AGENT);
}
__device__ __forceinline__ f16x8 ld_agent_f16x8(const half_t* p) {
    union { unsigned long long u[2]; f16x8 v; } c;
    c.u[0] = __hip_atomic_load((const unsigned long long*)p,
                               __ATOMIC_RELAXED, __HIP_MEMORY_SCOPE_AGENT);
    c.u[1] = __hip_atomic_load(((const unsigned long long*)p) + 1,
                               __ATOMIC_RELAXED, __HIP_MEMORY_SCOPE_AGENT);
    return c.v;
}

// ---------------------------------------------------------------------------
// One-time weight packing / conversion kernels
// ---------------------------------------------------------------------------
template<int KIH, int KHH>
__global__ __launch_bounds__(256) void conv_lstm_w(
    const float* __restrict__ Wih, const float* __restrict__ Whh,
    const float* __restrict__ bih, const float* __restrict__ bhh,
    half_t* __restrict__ Wcat, float* __restrict__ bsum)
{
    constexpr int K = KIH + KHH;
    const int j = blockIdx.x;
    const float* srcA = Wih + (size_t)j * KIH;
    const float* srcB = Whh + (size_t)j * KHH;
    half_t* dst = Wcat + (size_t)j * K;
    for (int k = threadIdx.x; k < KIH; k += 256) dst[k]       = (half_t)srcA[k];
    for (int k = threadIdx.x; k < KHH; k += 256) dst[KIH + k] = (half_t)srcB[k];
    if (threadIdx.x == 0) bsum[j] = bih[j] + bhh[j];
}

__global__ __launch_bounds__(256) void conv_mat(
    const float* __restrict__ src, half_t* __restrict__ dst, int n)
{
    for (int i = blockIdx.x * 256 + threadIdx.x; i < n; i += gridDim.x * 256)
        dst[i] = (half_t)src[i];
}

// ---------------------------------------------------------------------------
// Prenet (one-time, parallel over T*B rows): f16 output (T,B,PRE)
// ---------------------------------------------------------------------------
__global__ __launch_bounds__(256) void prenet_kernel(
    const float* __restrict__ din,
    const float* __restrict__ pW1, const float* __restrict__ pb1,
    const float* __restrict__ pW2, const float* __restrict__ pb2,
    half_t* __restrict__ xpre)
{
    __shared__ float xs[8][EMBD];
    __shared__ float h1s[8][PRE];
    const int tid = threadIdx.x;
    const int row0 = blockIdx.x * 8;

    for (int idx = tid; idx < 8 * EMBD; idx += 256) {
        int r = idx >> 9;
        int e = idx & 511;
        int rid = row0 + r;
        int t = rid >> 5;
        int b = rid & 31;
        float v = 0.f;
        if (t > 0) v = din[(size_t)b * EMBD * Tsteps + (size_t)e * Tsteps + (t - 1)];
        xs[r][e] = v;
    }
    __syncthreads();

    {
        float acc[8] = {0.f,0.f,0.f,0.f,0.f,0.f,0.f,0.f};
        const float* wr = pW1 + (size_t)tid * EMBD;
        for (int e = 0; e < EMBD; e += 4) {
            float4 wv = *(const float4*)(wr + e);
            #pragma unroll
            for (int r = 0; r < 8; ++r) {
                float4 xv = *(const float4*)&xs[r][e];
                acc[r] += wv.x * xv.x + wv.y * xv.y + wv.z * xv.z + wv.w * xv.w;
            }
        }
        float bias = pb1[tid];
        #pragma unroll
        for (int r = 0; r < 8; ++r) h1s[r][tid] = fmaxf(acc[r] + bias, 0.f);
    }
    __syncthreads();

    {
        float acc[8] = {0.f,0.f,0.f,0.f,0.f,0.f,0.f,0.f};
        const float* wr = pW2 + (size_t)tid * PRE;
        for (int e = 0; e < PRE; e += 4) {
            float4 wv = *(const float4*)(wr + e);
            #pragma unroll
            for (int r = 0; r < 8; ++r) {
                float4 xv = *(const float4*)&h1s[r][e];
                acc[r] += wv.x * xv.x + wv.y * xv.y + wv.z * xv.z + wv.w * xv.w;
            }
        }
        float bias = pb2[tid];
        #pragma unroll
        for (int r = 0; r < 8; ++r) {
            int rid = row0 + r;
            int t = rid >> 5;
            int b = rid & 31;
            xpre[(size_t)t * Bsz * PRE + (size_t)b * PRE + tid] =
                (half_t)fmaxf(acc[r] + bias, 0.f);
        }
    }
}

// ---------------------------------------------------------------------------
// Flat RMW-free device barrier, NO cache invalidates. All cross-block data
// moves via sc1 (write-through stores / L2-bypass loads), so no fence needed.
// Arrival: vmcnt drain + block barrier + tid0 sc1 flag store. 64 pollers per
// block poll 4 flags each with relaxed sc1 loads. ph is monotone.
// ---------------------------------------------------------------------------
__device__ __forceinline__ void gsync(unsigned* flags, unsigned ph)
{
    asm volatile("s_waitcnt vmcnt(0)" ::: "memory");   // stores committed
    __syncthreads();
    if (threadIdx.x == 0)
        __hip_atomic_store(flags + blockIdx.x * 16, ph,
                           __ATOMIC_RELAXED, __HIP_MEMORY_SCOPE_AGENT);
    if (threadIdx.x < 64) {
        const unsigned* f = flags + threadIdx.x * 64;   // 4 flags, stride 16
        for (;;) {
            unsigned a = ld_agent_u32(f);
            unsigned b = ld_agent_u32(f + 16);
            unsigned c = ld_agent_u32(f + 32);
            unsigned d = ld_agent_u32(f + 48);
            unsigned m = min(min(a, b), min(c, d));
            if (m >= ph) break;
            __builtin_amdgcn_s_sleep(2);
        }
    }
    __syncthreads();
}

// ---------------------------------------------------------------------------
// Persistent decoder. 256 blocks x 512 threads (1 block/CU). LSTM weights in
// LDS for all 400 steps. c-states in registers. 2 barriers/step:
//   phase1: aLSTM_t || dLSTM_{t-1}   phase2: att_t || outproj_{t-1}
// B-fragments prefetched into register arrays (sc1), MFMA chains after.
// ---------------------------------------------------------------------------
__global__ __launch_bounds__(512, 1) void decoder_persistent(
    const half_t* __restrict__ Wcat_a, const float* __restrict__ bsum_a,
    const half_t* __restrict__ Wcat_d, const float* __restrict__ bsum_d,
    const half_t* __restrict__ Wo, const float* __restrict__ ob,
    const half_t* __restrict__ xpre,
    const float* __restrict__ attWp, const float* __restrict__ attbp,
    const int* __restrict__ mlen, const half_t* __restrict__ mem16,
    half_t* __restrict__ ah0, half_t* __restrict__ ah1,
    half_t* __restrict__ dh0, half_t* __restrict__ dh1,
    half_t* __restrict__ ctx0, half_t* __restrict__ ctx1,
    float* __restrict__ mean0, float* __restrict__ mean1,
    float* __restrict__ logits, float* __restrict__ aligns,
    float* __restrict__ ps,
    unsigned* flags)
{
    const int blk   = blockIdx.x;
    const int tid   = threadIdx.x;
    const int wave  = tid >> 6;
    const int lane  = tid & 63;
    const int btile = wave & 1;
    const int kq    = wave >> 1;
    const int m15   = lane & 15;
    const int kh    = lane >> 4;
    const int u0    = blk << 2;
    const int bb    = (btile << 4) + m15;

    __shared__ __align__(16) half_t wAl[16 * LDA_A];   // 57.6 KB
    __shared__ __align__(16) half_t wDl[16 * LDA_D];   // 82.2 KB
    __shared__ float gred[4][2][16][16];               // 8 KB
    __shared__ float wsh[Lmem];                        // 2 KB
    __shared__ float lred[16][33];                     // 2.1 KB
    __shared__ float wred8[8][2];
    __shared__ float bc2[2];

    // ---- stage weight rows into LDS (one-time) ----
    for (int g = tid; g < 16 * (KA / 8); g += 512) {
        int r = g / (KA / 8);
        int c = (g - r * (KA / 8)) * 8;
        int jr = (r >> 2) * 1024 + u0 + (r & 3);
        *(f16x8*)(wAl + r * LDA_A + c) = *(const f16x8*)(Wcat_a + (size_t)jr * KA + c);
    }
    for (int g = tid; g < 16 * (KD / 8); g += 512) {
        int r = g / (KD / 8);
        int c = (g - r * (KD / 8)) * 8;
        int jr = (r >> 2) * 1024 + u0 + (r & 3);
        *(f16x8*)(wDl + r * LDA_D + c) = *(const f16x8*)(Wcat_d + (size_t)jr * KD + c);
    }
    float bsA[4] = {0.f,0.f,0.f,0.f}, bsD[4] = {0.f,0.f,0.f,0.f};
    float cA = 0.f, cD = 0.f;
    if (tid < 128) {
        const int ul = tid >> 5;
        #pragma unroll
        for (int gi = 0; gi < 4; ++gi) {
            bsA[gi] = bsum_a[gi * 1024 + u0 + ul];
            bsD[gi] = bsum_d[gi * 1024 + u0 + ul];
        }
    }
    const half_t* lA = wAl + m15 * LDA_A + kq * KAQ + (kh << 3);
    const half_t* lD = wDl + m15 * LDA_D + kq * KDQ + (kh << 3);
    __syncthreads();

    unsigned ph = 0;

    for (int t = 0; t <= Tsteps; ++t) {
        const int par = t & 1;
        half_t*       ah_cur  = par ? ah1 : ah0;
        const half_t* ah_prv  = par ? ah0 : ah1;
        half_t*       ctx_cur = par ? ctx1 : ctx0;
        const half_t* ctx_prv = par ? ctx0 : ctx1;
        float*        mn_cur  = par ? mean1 : mean0;
        const float*  mn_prv  = par ? mean0 : mean1;
        half_t*       dh_s    = par ? dh0 : dh1;
        const half_t* dh_prv  = par ? dh1 : dh0;

        // ================= PHASE 1: aLSTM_t || dLSTM_{t-1} =================
        {
            f16x8 bvA[NMA];
            f16x8 bvD[NMD];
            if (t < Tsteps) {            // prefetch all aLSTM B-frags (sc1)
                const half_t* s0 = xpre + (size_t)t * Bsz * PRE;
                #pragma unroll
                for (int i = 0; i < NMA; ++i) {
                    const int kg = kq * KAQ + i * 32 + (kh << 3);
                    const half_t* bp = (kg < PRE)        ? (s0 + bb * PRE + kg)
                                     : (kg < PRE + ENCD) ? (ctx_prv + bb * ENCD + (kg - PRE))
                                                         : (ah_prv + bb * ARNN + (kg - PRE - ENCD));
                    bvA[i] = ld_agent_f16x8(bp);
                }
            }
            if (t > 0) {                 // prefetch all dLSTM B-frags (sc1)
                #pragma unroll
                for (int i = 0; i < NMD; ++i) {
                    const int kg = kq * KDQ + i * 32 + (kh << 3);
                    const half_t* bp = (kg < ARNN)        ? (ah_prv + bb * ARNN + kg)
                                     : (kg < ARNN + ENCD) ? (ctx_prv + bb * ENCD + (kg - ARNN))
                                                          : (dh_prv + bb * DRNN + (kg - ARNN - ENCD));
                    bvD[i] = ld_agent_f16x8(bp);
                }
            }
            if (t < Tsteps) {
                f32x4 accA = {0.f,0.f,0.f,0.f};
                #pragma unroll
                for (int i = 0; i < NMA; ++i) {
                    f16x8 av = *(const f16x8*)(lA + i * 32);
                    accA = __builtin_amdgcn_mfma_f32_16x16x32_f16(av, bvA[i], accA, 0, 0, 0);
                }
                #pragma unroll
                for (int r = 0; r < 4; ++r)
                    gred[kq][btile][(kh << 2) + r][m15] = accA[r];
                __syncthreads();
                if (tid < 128) {
                    const int ul = tid >> 5;
                    const int bq = tid & 31;
                    const int bt = bq >> 4;
                    const int nn = bq & 15;
                    float g[4];
                    #pragma unroll
                    for (int gi = 0; gi < 4; ++gi) {
                        const int mr = (gi << 2) + ul;
                        g[gi] = gred[0][bt][mr][nn] + gred[1][bt][mr][nn]
                              + gred[2][bt][mr][nn] + gred[3][bt][mr][nn] + bsA[gi];
                    }
                    float si = 1.f / (1.f + expf(-g[0]));
                    float sf = 1.f / (1.f + expf(-g[1]));
                    float so = 1.f / (1.f + expf(-g[3]));
                    cA = sf * cA + si * tanhf(g[2]);
                    st_agent_f16(&ah_cur[bq * 1024 + u0 + ul], (half_t)(so * tanhf(cA)));
                }
                __syncthreads();
            }
            if (t > 0) {
                f32x4 accD = {0.f,0.f,0.f,0.f};
                #pragma unroll
                for (int i = 0; i < NMD; ++i) {
                    f16x8 av = *(const f16x8*)(lD + i * 32);
                    accD = __builtin_amdgcn_mfma_f32_16x16x32_f16(av, bvD[i], accD, 0, 0, 0);
                }
                #pragma unroll
                for (int r = 0; r < 4; ++r)
                    gred[kq][btile][(kh << 2) + r][m15] = accD[r];
                __syncthreads();
                if (tid < 128) {
                    const int ul = tid >> 5;
                    const int bq = tid & 31;
                    const int bt = bq >> 4;
                    const int nn = bq & 15;
                    float g[4];
                    #pragma unroll
                    for (int gi = 0; gi < 4; ++gi) {
                        const int mr = (gi << 2) + ul;
                        g[gi] = gred[0][bt][mr][nn] + gred[1][bt][mr][nn]
                              + gred[2][bt][mr][nn] + gred[3][bt][mr][nn] + bsD[gi];
                    }
                    float si = 1.f / (1.f + expf(-g[0]));
                    float sf = 1.f / (1.f + expf(-g[1]));
                    float so = 1.f / (1.f + expf(-g[3]));
                    cD = sf * cD + si * tanhf(g[2]);
                    st_agent_f16(&dh_s[bq * 1024 + u0 + ul], (half_t)(so * tanhf(cD)));
                }
            }
        }
        ++ph; gsync(flags, ph);

        // ================= PHASE 2: att_t || outproj_{t-1} =================
        if (t < Tsteps) {
            const int abt = blk >> 3;   // batch
            const int dt  = blk & 7;    // d-tile
            // params = ah @ attWp.T : thread k reads 2 halves of ah (sc1)
            float p0, p1;
            {
                union { unsigned u; _Float16 h[2]; } a;
                a.u = ld_agent_u32((const unsigned*)(ah_cur + abt * ARNN + 2 * tid));
                float a0 = (float)a.h[0], a1 = (float)a.h[1];
                float2 w0 = *(const float2*)(attWp + 2 * tid);
                float2 w1 = *(const float2*)(attWp + ARNN + 2 * tid);
                p0 = a0 * w0.x + a1 * w0.y;
                p1 = a0 * w1.x + a1 * w1.y;
            }
            #pragma unroll
            for (int off = 32; off > 0; off >>= 1) {
                p0 += __shfl_down(p0, off, 64);
                p1 += __shfl_down(p1, off, 64);
            }
            if (lane == 0) { wred8[wave][0] = p0; wred8[wave][1] = p1; }
            __syncthreads();
            if (tid == 0) {
                float q0 = attbp[0], q1 = attbp[1];
                #pragma unroll
                for (int w = 0; w < 8; ++w) { q0 += wred8[w][0]; q1 += wred8[w][1]; }
                float mn = ld_agent_f32(&mn_prv[abt]) + expf(q0) * 1.0f;  // MEAN_COEFF
                float sc = expf(q1) * 10.0f;                              // SCALE_COEFF
                if (dt == 0) {
                    st_agent_f32(&mn_cur[abt], mn);
                    st_agent_f32(&ps[(size_t)abt * Tsteps * 2 + (size_t)t * 2 + 0], q0);
                    st_agent_f32(&ps[(size_t)abt * Tsteps * 2 + (size_t)t * 2 + 1], q1);
                }
                bc2[0] = mn; bc2[1] = sc;
            }
            __syncthreads();
            const float mn = bc2[0], sc = bc2[1];
            const float inv_s = 1.f / sc;
            const float coef = 0.3989422804014327f * inv_s;
            const int len = mlen[abt];
            {
                float z = ((float)tid - mn) * inv_s;
                float wv = (tid < len) ? expf(-0.5f * z * z) * coef : 0.f;
                wsh[tid] = wv;
                if (dt == 0)
                    st_agent_f32(&aligns[(size_t)abt * Tsteps * Lmem + (size_t)t * Lmem + tid], wv);
            }
            __syncthreads();
            // ctx over +-9 sigma window: thread = (d-octet = wave, row = lane)
            int lo = (int)fmaxf(0.f, floorf(mn - 9.f * sc));
            int hi = (int)fminf((float)len, ceilf(mn + 9.f * sc) + 1.f);
            const int d8 = (dt << 6) + (wave << 3);
            const half_t* mb = mem16 + (size_t)abt * Lmem * ENCD + d8;
            float acc[8] = {0.f,0.f,0.f,0.f,0.f,0.f,0.f,0.f};
            for (int l = lo + lane; l < hi; l += 64) {
                f16x8 mv = *(const f16x8*)(mb + (size_t)l * ENCD);   // plain, L2-hot
                float w = wsh[l];
                #pragma unroll
                for (int j = 0; j < 8; ++j) acc[j] += w * (float)mv[j];
            }
            #pragma unroll
            for (int off = 32; off > 0; off >>= 1) {
                #pragma unroll
                for (int j = 0; j < 8; ++j) acc[j] += __shfl_down(acc[j], off, 64);
            }
            if (lane == 0) {
                #pragma unroll
                for (int j = 0; j < 4; ++j) {
                    union { unsigned u; _Float16 h[2]; } pk;
                    pk.h[0] = (_Float16)acc[2 * j];
                    pk.h[1] = (_Float16)acc[2 * j + 1];
                    st_agent_u32((unsigned*)(ctx_cur + abt * ENCD + d8 + 2 * j), pk.u);
                }
            }
        }
        if (t > 0) {
            // outproj for step t-1: row n = blk; prefetch acts (sc1) then dot
            const int b_o = tid & 31;
            const int ks  = tid >> 5;
            const half_t* wrow = Wo + (size_t)blk * (DRNN + ENCD) + ks * 96;
            f16x8 wv[12], av[12];
            #pragma unroll
            for (int c8 = 0; c8 < 12; ++c8) {
                const int k = ks * 96 + c8 * 8;
                wv[c8] = *(const f16x8*)(wrow + c8 * 8);   // plain, L2-hot
                const half_t* ap = (k < DRNN) ? (dh_s + b_o * DRNN + k)
                                              : (ctx_prv + b_o * ENCD + (k - DRNN));
                av[c8] = ld_agent_f16x8(ap);
            }
            float outacc = 0.f;
            #pragma unroll
            for (int c8 = 0; c8 < 12; ++c8)
                #pragma unroll
                for (int e = 0; e < 8; ++e)
                    outacc += (float)wv[c8][e] * (float)av[c8][e];
            lred[ks][b_o] = outacc;
            __syncthreads();
            if (tid < 32) {
                float s = 0.f;
                #pragma unroll
                for (int q = 0; q < 16; ++q) s += lred[q][tid];
                st_agent_f32(&logits[(size_t)tid * Tsteps * NSYM + (size_t)(t - 1) * NSYM + blk],
                             s + ob[blk]);
            }
        }
        if (t < Tsteps) { ++ph; gsync(flags, ph); }
    }
}

// ---------------------------------------------------------------------------
extern "C" void kernel_launch(void* const* d_in, const int* in_sizes, int n_in,
                              void* d_out, int out_size, void* d_ws, size_t ws_size,
                              hipStream_t stream)
{
    (void)in_sizes; (void)n_in; (void)out_size; (void)ws_size;
    const float* memory = (const float*)d_in[0];
    const float* din    = (const float*)d_in[1];
    const int*   mlen   = (const int*)d_in[2];
    const float* pW1    = (const float*)d_in[3];
    const float* pb1    = (const float*)d_in[4];
    const float* pW2    = (const float*)d_in[5];
    const float* pb2    = (const float*)d_in[6];
    const float* aWih   = (const float*)d_in[7];
    const float* aWhh   = (const float*)d_in[8];
    const float* abih   = (const float*)d_in[9];
    const float* abhh   = (const float*)d_in[10];
    const float* attWp  = (const float*)d_in[11];
    const float* attbp  = (const float*)d_in[12];
    const float* dWih   = (const float*)d_in[13];
    const float* dWhh   = (const float*)d_in[14];
    const float* dbih   = (const float*)d_in[15];
    const float* dbhh   = (const float*)d_in[16];
    const float* oW     = (const float*)d_in[17];
    const float* ob     = (const float*)d_in[18];

    float* logits = (float*)d_out;
    float* aligns = logits + (size_t)Bsz * Tsteps * NSYM;
    float* ps     = aligns + (size_t)Bsz * Tsteps * Lmem;

    char* base = (char*)d_ws;
    auto alloc = [&](size_t bytes) -> char* {
        char* p = base; base += (bytes + 255) & ~(size_t)255; return p;
    };
    half_t* Wcat_a = (half_t*)alloc((size_t)4096 * KA * 2);
    half_t* Wcat_d = (half_t*)alloc((size_t)4096 * KD * 2);
    half_t* Wo     = (half_t*)alloc((size_t)NSYM * (DRNN + ENCD) * 2);
    float*  bsum_a = (float*)alloc(4096 * 4);
    float*  bsum_d = (float*)alloc(4096 * 4);
    half_t* xpre   = (half_t*)alloc((size_t)Tsteps * Bsz * PRE * 2);
    half_t* mem16  = (half_t*)alloc((size_t)Bsz * Lmem * ENCD * 2);
    half_t* ah0    = (half_t*)alloc(Bsz * ARNN * 2);
    half_t* ah1    = (half_t*)alloc(Bsz * ARNN * 2);
    half_t* dh0    = (half_t*)alloc(Bsz * DRNN * 2);
    half_t* dh1    = (half_t*)alloc(Bsz * DRNN * 2);
    half_t* ctx0   = (half_t*)alloc(Bsz * ENCD * 2);
    half_t* ctx1   = (half_t*)alloc(Bsz * ENCD * 2);
    float*  mean0  = (float*)alloc(Bsz * 4);
    float*  mean1  = (float*)alloc(Bsz * 4);
    unsigned* flags = (unsigned*)alloc(256 * 16 * 4);

    (void)hipMemsetAsync(ah1,   0, Bsz * ARNN * 2, stream);
    (void)hipMemsetAsync(dh1,   0, Bsz * DRNN * 2, stream);
    (void)hipMemsetAsync(ctx1,  0, Bsz * ENCD * 2, stream);
    (void)hipMemsetAsync(mean0, 0, Bsz * 4, stream);
    (void)hipMemsetAsync(mean1, 0, Bsz * 4, stream);
    (void)hipMemsetAsync(flags, 0, 256 * 16 * 4, stream);

    conv_lstm_w<PRE + ENCD, ARNN><<<4096, 256, 0, stream>>>(
        aWih, aWhh, abih, abhh, Wcat_a, bsum_a);
    conv_lstm_w<ARNN + ENCD, DRNN><<<4096, 256, 0, stream>>>(
        dWih, dWhh, dbih, dbhh, Wcat_d, bsum_d);
    conv_mat<<<768, 256, 0, stream>>>(oW, Wo, NSYM * (DRNN + ENCD));
    conv_mat<<<4096, 256, 0, stream>>>(memory, mem16, Bsz * Lmem * ENCD);
    prenet_kernel<<<Tsteps * Bsz / 8, 256, 0, stream>>>(din, pW1, pb1, pW2, pb2, xpre);

    decoder_persistent<<<256, 512, 0, stream>>>(
        Wcat_a, bsum_a, Wcat_d, bsum_d, Wo, ob, xpre,
        attWp, attbp, mlen, mem16,
        ah0, ah1, dh0, dh1, ctx0, ctx1, mean0, mean1,
        logits, aligns, ps,
        flags);
}

// Round 8
// 14293.837 us; speedup vs baseline: 4.3430x; 1.1375x over previous
//
#include <hip/hip_runtime.h>
#include <math.h>

// Problem constants (from reference)
#define Bsz   32
#define Lmem  512
#define Tsteps 400
#define EMBD  512
#define PRE   256
#define ENCD  512
#define ARNN  1024
#define DRNN  1024
#define NSYM  256
// MEAN_COEFF = 1.0f, SCALE_COEFF = 10.0f

typedef _Float16 f16x8 __attribute__((ext_vector_type(8)));
typedef float    f32x4 __attribute__((ext_vector_type(4)));
typedef _Float16 half_t;

#define KA  (PRE + ENCD + ARNN)    // 1792
#define KAQ (KA / 4)               // 448
#define NMA (KAQ / 32)             // 14
#define KD  (ARNN + ENCD + DRNN)   // 2560
#define KDQ (KD / 4)               // 640
#define NMD (KDQ / 32)             // 20
#define LDA_A 1800                 // KA + 8 pad
#define LDA_D 2568                 // KD + 8 pad

// ---- agent-scope (cross-XCD) access: sc1 bypasses the non-coherent per-XCD
// L2. Mutable cross-block data: sc1 loads+stores. Read-only data: plain loads
// (L2-hot). No cache-invalidate fences anywhere.
__device__ __forceinline__ void st_agent_f16(half_t* p, half_t v) {
    __hip_atomic_store((unsigned short*)p, __builtin_bit_cast(unsigned short, v),
                       __ATOMIC_RELAXED, __HIP_MEMORY_SCOPE_AGENT);
}
__device__ __forceinline__ void st_agent_f32(float* p, float v) {
    __hip_atomic_store(p, v, __ATOMIC_RELAXED, __HIP_MEMORY_SCOPE_AGENT);
}
__device__ __forceinline__ void st_agent_u32(unsigned* p, unsigned v) {
    __hip_atomic_store(p, v, __ATOMIC_RELAXED, __HIP_MEMORY_SCOPE_AGENT);
}
__device__ __forceinline__ float ld_agent_f32(const float* p) {
    return __hip_atomic_load(p, __ATOMIC_RELAXED, __HIP_MEMORY_SCOPE_AGENT);
}
__device__ __forceinline__ unsigned ld_agent_u32(const unsigned* p) {
    return __hip_atomic_load(p, __ATOMIC_RELAXED, __HIP_MEMORY_SCOPE_AGENT);
}
__device__ __forceinline__ f16x8 ld_agent_f16x8(const half_t* p) {
    union { unsigned long long u[2]; f16x8 v; } c;
    c.u[0] = __hip_atomic_load((const unsigned long long*)p,
                               __ATOMIC_RELAXED, __HIP_MEMORY_SCOPE_AGENT);
    c.u[1] = __hip_atomic_load(((const unsigned long long*)p) + 1,
                               __ATOMIC_RELAXED, __HIP_MEMORY_SCOPE_AGENT);
    return c.v;
}

// ---------------------------------------------------------------------------
// One-time weight packing / conversion kernels
// ---------------------------------------------------------------------------
template<int KIH, int KHH>
__global__ __launch_bounds__(256) void conv_lstm_w(
    const float* __restrict__ Wih, const float* __restrict__ Whh,
    const float* __restrict__ bih, const float* __restrict__ bhh,
    half_t* __restrict__ Wcat, float* __restrict__ bsum)
{
    constexpr int K = KIH + KHH;
    const int j = blockIdx.x;
    const float* srcA = Wih + (size_t)j * KIH;
    const float* srcB = Whh + (size_t)j * KHH;
    half_t* dst = Wcat + (size_t)j * K;
    for (int k = threadIdx.x; k < KIH; k += 256) dst[k]       = (half_t)srcA[k];
    for (int k = threadIdx.x; k < KHH; k += 256) dst[KIH + k] = (half_t)srcB[k];
    if (threadIdx.x == 0) bsum[j] = bih[j] + bhh[j];
}

__global__ __launch_bounds__(256) void conv_mat(
    const float* __restrict__ src, half_t* __restrict__ dst, int n)
{
    for (int i = blockIdx.x * 256 + threadIdx.x; i < n; i += gridDim.x * 256)
        dst[i] = (half_t)src[i];
}

// ---------------------------------------------------------------------------
// Prenet (one-time, parallel over T*B rows): f16 output (T,B,PRE)
// ---------------------------------------------------------------------------
__global__ __launch_bounds__(256) void prenet_kernel(
    const float* __restrict__ din,
    const float* __restrict__ pW1, const float* __restrict__ pb1,
    const float* __restrict__ pW2, const float* __restrict__ pb2,
    half_t* __restrict__ xpre)
{
    __shared__ float xs[8][EMBD];
    __shared__ float h1s[8][PRE];
    const int tid = threadIdx.x;
    const int row0 = blockIdx.x * 8;

    for (int idx = tid; idx < 8 * EMBD; idx += 256) {
        int r = idx >> 9;
        int e = idx & 511;
        int rid = row0 + r;
        int t = rid >> 5;
        int b = rid & 31;
        float v = 0.f;
        if (t > 0) v = din[(size_t)b * EMBD * Tsteps + (size_t)e * Tsteps + (t - 1)];
        xs[r][e] = v;
    }
    __syncthreads();

    {
        float acc[8] = {0.f,0.f,0.f,0.f,0.f,0.f,0.f,0.f};
        const float* wr = pW1 + (size_t)tid * EMBD;
        for (int e = 0; e < EMBD; e += 4) {
            float4 wv = *(const float4*)(wr + e);
            #pragma unroll
            for (int r = 0; r < 8; ++r) {
                float4 xv = *(const float4*)&xs[r][e];
                acc[r] += wv.x * xv.x + wv.y * xv.y + wv.z * xv.z + wv.w * xv.w;
            }
        }
        float bias = pb1[tid];
        #pragma unroll
        for (int r = 0; r < 8; ++r) h1s[r][tid] = fmaxf(acc[r] + bias, 0.f);
    }
    __syncthreads();

    {
        float acc[8] = {0.f,0.f,0.f,0.f,0.f,0.f,0.f,0.f};
        const float* wr = pW2 + (size_t)tid * PRE;
        for (int e = 0; e < PRE; e += 4) {
            float4 wv = *(const float4*)(wr + e);
            #pragma unroll
            for (int r = 0; r < 8; ++r) {
                float4 xv = *(const float4*)&h1s[r][e];
                acc[r] += wv.x * xv.x + wv.y * xv.y + wv.z * xv.z + wv.w * xv.w;
            }
        }
        float bias = pb2[tid];
        #pragma unroll
        for (int r = 0; r < 8; ++r) {
            int rid = row0 + r;
            int t = rid >> 5;
            int b = rid & 31;
            xpre[(size_t)t * Bsz * PRE + (size_t)b * PRE + tid] =
                (half_t)fmaxf(acc[r] + bias, 0.f);
        }
    }
}

// ---------------------------------------------------------------------------
// Split-phase RMW-free device barrier (256 blocks). arrive = drain stores +
// block barrier + tid0 sc1 flag store. wait = 64 pollers x 4 relaxed sc1
// flag loads + block barrier. Prefetch loads go between arrive and wait.
// ---------------------------------------------------------------------------
__device__ __forceinline__ void g_arrive(unsigned* flags, unsigned ph)
{
    asm volatile("s_waitcnt vmcnt(0)" ::: "memory");
    __syncthreads();
    if (threadIdx.x == 0)
        __hip_atomic_store(flags + blockIdx.x * 16, ph,
                           __ATOMIC_RELAXED, __HIP_MEMORY_SCOPE_AGENT);
}
__device__ __forceinline__ void g_wait(unsigned* flags, unsigned ph)
{
    if (threadIdx.x < 64) {
        const unsigned* f = flags + threadIdx.x * 64;
        for (;;) {
            unsigned a = ld_agent_u32(f);
            unsigned b = ld_agent_u32(f + 16);
            unsigned c = ld_agent_u32(f + 32);
            unsigned d = ld_agent_u32(f + 48);
            if (min(min(a, b), min(c, d)) >= ph) break;
            __builtin_amdgcn_s_sleep(2);
        }
    }
    __syncthreads();
}

// ---------------------------------------------------------------------------
// Persistent decoder. 256 blocks x 512 threads. Weights in LDS all 400 steps.
// 2 barriers/step; B-fragments for the NEXT phase1 are prefetched between
// arrive(ph2) and wait(ph2) (all but the ctx segment, which loads post-wait).
// Concurrent aLSTM/dLSTM epilogues (threads 0-127 / 128-255).
// ---------------------------------------------------------------------------
__global__ __launch_bounds__(512, 1) void decoder_persistent(
    const half_t* __restrict__ Wcat_a, const float* __restrict__ bsum_a,
    const half_t* __restrict__ Wcat_d, const float* __restrict__ bsum_d,
    const half_t* __restrict__ Wo, const float* __restrict__ ob,
    const half_t* __restrict__ xpre,
    const float* __restrict__ attWp, const float* __restrict__ attbp,
    const int* __restrict__ mlen, const half_t* __restrict__ mem16,
    half_t* __restrict__ ah0, half_t* __restrict__ ah1,
    half_t* __restrict__ dh0, half_t* __restrict__ dh1,
    half_t* __restrict__ ctx0, half_t* __restrict__ ctx1,
    float* __restrict__ mean0, float* __restrict__ mean1,
    float* __restrict__ logits, float* __restrict__ aligns,
    float* __restrict__ ps,
    unsigned* flags)
{
    const int blk   = blockIdx.x;
    const int tid   = threadIdx.x;
    const int wave  = tid >> 6;
    const int lane  = tid & 63;
    const int btile = wave & 1;
    const int kq    = wave >> 1;
    const int m15   = lane & 15;
    const int kh    = lane >> 4;
    const int u0    = blk << 2;
    const int bb    = (btile << 4) + m15;

    __shared__ __align__(16) half_t wAl[16 * LDA_A];   // 57.6 KB
    __shared__ __align__(16) half_t wDl[16 * LDA_D];   // 82.2 KB
    __shared__ float gredA[4][2][16][16];              // 8 KB
    __shared__ float gredD[4][2][16][16];              // 8 KB
    __shared__ float wsh[Lmem];                        // 2 KB
    __shared__ float lred[16][33];                     // 2.1 KB
    __shared__ float wred8[8][2];
    __shared__ float bc2[2];

    // ---- stage weight rows into LDS (one-time) ----
    for (int g = tid; g < 16 * (KA / 8); g += 512) {
        int r = g / (KA / 8);
        int c = (g - r * (KA / 8)) * 8;
        int jr = (r >> 2) * 1024 + u0 + (r & 3);
        *(f16x8*)(wAl + r * LDA_A + c) = *(const f16x8*)(Wcat_a + (size_t)jr * KA + c);
    }
    for (int g = tid; g < 16 * (KD / 8); g += 512) {
        int r = g / (KD / 8);
        int c = (g - r * (KD / 8)) * 8;
        int jr = (r >> 2) * 1024 + u0 + (r & 3);
        *(f16x8*)(wDl + r * LDA_D + c) = *(const f16x8*)(Wcat_d + (size_t)jr * KD + c);
    }
    // epilogue biases: A -> threads 0..127, D -> threads 128..255
    float bsA[4] = {0.f,0.f,0.f,0.f}, bsD[4] = {0.f,0.f,0.f,0.f};
    float cA = 0.f, cD = 0.f;
    if (tid < 128) {
        const int ul = tid >> 5;
        #pragma unroll
        for (int gi = 0; gi < 4; ++gi) bsA[gi] = bsum_a[gi * 1024 + u0 + ul];
    } else if (tid < 256) {
        const int ul = (tid - 128) >> 5;
        #pragma unroll
        for (int gi = 0; gi < 4; ++gi) bsD[gi] = bsum_d[gi * 1024 + u0 + ul];
    }
    const half_t* lA = wAl + m15 * LDA_A + kq * KAQ + (kh << 3);
    const half_t* lD = wDl + m15 * LDA_D + kq * KDQ + (kh << 3);
    __syncthreads();

    // ---- initial bvA load for t=0 (ctx1/ah1 are zeroed; xpre plain) ----
    f16x8 bvA[NMA], bvD[NMD];
    {
        const half_t* s0 = xpre;
        #pragma unroll
        for (int i = 0; i < NMA; ++i) {
            const int kg = kq * KAQ + i * 32 + (kh << 3);
            if (kg < PRE)             bvA[i] = *(const f16x8*)(s0 + bb * PRE + kg);
            else if (kg < PRE + ENCD) bvA[i] = ld_agent_f16x8(ctx1 + bb * ENCD + (kg - PRE));
            else                      bvA[i] = ld_agent_f16x8(ah1 + bb * ARNN + (kg - PRE - ENCD));
        }
    }

    unsigned ph = 0;

    for (int t = 0; t <= Tsteps; ++t) {
        const int par = t & 1;
        half_t*       ah_cur  = par ? ah1 : ah0;
        half_t*       ctx_cur = par ? ctx1 : ctx0;
        const half_t* ctx_prv = par ? ctx0 : ctx1;
        float*        mn_cur  = par ? mean1 : mean0;
        const float*  mn_prv  = par ? mean0 : mean1;
        half_t*       dh_s    = par ? dh0 : dh1;

        // ================= PHASE 1: aLSTM_t || dLSTM_{t-1} =================
        if (t < Tsteps) {
            f32x4 accA = {0.f,0.f,0.f,0.f};
            #pragma unroll
            for (int i = 0; i < NMA; ++i) {
                f16x8 av = *(const f16x8*)(lA + i * 32);
                accA = __builtin_amdgcn_mfma_f32_16x16x32_f16(av, bvA[i], accA, 0, 0, 0);
            }
            #pragma unroll
            for (int r = 0; r < 4; ++r)
                gredA[kq][btile][(kh << 2) + r][m15] = accA[r];
        }
        if (t > 0) {
            f32x4 accD = {0.f,0.f,0.f,0.f};
            #pragma unroll
            for (int i = 0; i < NMD; ++i) {
                f16x8 av = *(const f16x8*)(lD + i * 32);
                accD = __builtin_amdgcn_mfma_f32_16x16x32_f16(av, bvD[i], accD, 0, 0, 0);
            }
            #pragma unroll
            for (int r = 0; r < 4; ++r)
                gredD[kq][btile][(kh << 2) + r][m15] = accD[r];
        }
        __syncthreads();
        // concurrent epilogues: A on threads 0..127, D on threads 128..255
        if (tid < 128) {
            if (t < Tsteps) {
                const int ul = tid >> 5;
                const int bq = tid & 31;
                const int bt = bq >> 4;
                const int nn = bq & 15;
                float g[4];
                #pragma unroll
                for (int gi = 0; gi < 4; ++gi) {
                    const int mr = (gi << 2) + ul;
                    g[gi] = gredA[0][bt][mr][nn] + gredA[1][bt][mr][nn]
                          + gredA[2][bt][mr][nn] + gredA[3][bt][mr][nn] + bsA[gi];
                }
                float si = 1.f / (1.f + expf(-g[0]));
                float sf = 1.f / (1.f + expf(-g[1]));
                float so = 1.f / (1.f + expf(-g[3]));
                cA = sf * cA + si * tanhf(g[2]);
                st_agent_f16(&ah_cur[bq * 1024 + u0 + ul], (half_t)(so * tanhf(cA)));
            }
        } else if (tid < 256) {
            if (t > 0) {
                const int lt = tid - 128;
                const int ul = lt >> 5;
                const int bq = lt & 31;
                const int bt = bq >> 4;
                const int nn = bq & 15;
                float g[4];
                #pragma unroll
                for (int gi = 0; gi < 4; ++gi) {
                    const int mr = (gi << 2) + ul;
                    g[gi] = gredD[0][bt][mr][nn] + gredD[1][bt][mr][nn]
                          + gredD[2][bt][mr][nn] + gredD[3][bt][mr][nn] + bsD[gi];
                }
                float si = 1.f / (1.f + expf(-g[0]));
                float sf = 1.f / (1.f + expf(-g[1]));
                float so = 1.f / (1.f + expf(-g[3]));
                cD = sf * cD + si * tanhf(g[2]);
                st_agent_f16(&dh_s[bq * 1024 + u0 + ul], (half_t)(so * tanhf(cD)));
            }
        }
        ++ph; g_arrive(flags, ph); g_wait(flags, ph);

        // ================= PHASE 2: att_t || outproj_{t-1} =================
        if (t < Tsteps) {
            const int abt = blk >> 3;   // batch
            const int dt  = blk & 7;    // d-tile
            float p0, p1;
            {
                union { unsigned u; _Float16 h[2]; } a;
                a.u = ld_agent_u32((const unsigned*)(ah_cur + abt * ARNN + 2 * tid));
                float a0 = (float)a.h[0], a1 = (float)a.h[1];
                float2 w0 = *(const float2*)(attWp + 2 * tid);
                float2 w1 = *(const float2*)(attWp + ARNN + 2 * tid);
                p0 = a0 * w0.x + a1 * w0.y;
                p1 = a0 * w1.x + a1 * w1.y;
            }
            #pragma unroll
            for (int off = 32; off > 0; off >>= 1) {
                p0 += __shfl_down(p0, off, 64);
                p1 += __shfl_down(p1, off, 64);
            }
            if (lane == 0) { wred8[wave][0] = p0; wred8[wave][1] = p1; }
            __syncthreads();
            if (tid == 0) {
                float q0 = attbp[0], q1 = attbp[1];
                #pragma unroll
                for (int w = 0; w < 8; ++w) { q0 += wred8[w][0]; q1 += wred8[w][1]; }
                float mn = ld_agent_f32(&mn_prv[abt]) + expf(q0) * 1.0f;  // MEAN_COEFF
                float sc = expf(q1) * 10.0f;                              // SCALE_COEFF
                if (dt == 0) {
                    st_agent_f32(&mn_cur[abt], mn);
                    st_agent_f32(&ps[(size_t)abt * Tsteps * 2 + (size_t)t * 2 + 0], q0);
                    st_agent_f32(&ps[(size_t)abt * Tsteps * 2 + (size_t)t * 2 + 1], q1);
                }
                bc2[0] = mn; bc2[1] = sc;
            }
            __syncthreads();
            const float mn = bc2[0], sc = bc2[1];
            const float inv_s = 1.f / sc;
            const float coef = 0.3989422804014327f * inv_s;
            const int len = mlen[abt];
            {
                float z = ((float)tid - mn) * inv_s;
                float wv = (tid < len) ? expf(-0.5f * z * z) * coef : 0.f;
                wsh[tid] = wv;
                if (dt == 0)
                    st_agent_f32(&aligns[(size_t)abt * Tsteps * Lmem + (size_t)t * Lmem + tid], wv);
            }
            __syncthreads();
            int lo = (int)fmaxf(0.f, floorf(mn - 9.f * sc));
            int hi = (int)fminf((float)len, ceilf(mn + 9.f * sc) + 1.f);
            const int d8 = (dt << 6) + (wave << 3);
            const half_t* mb = mem16 + (size_t)abt * Lmem * ENCD + d8;
            float acc[8] = {0.f,0.f,0.f,0.f,0.f,0.f,0.f,0.f};
            for (int l = lo + lane; l < hi; l += 64) {
                f16x8 mv = *(const f16x8*)(mb + (size_t)l * ENCD);   // plain, L2-hot
                float w = wsh[l];
                #pragma unroll
                for (int j = 0; j < 8; ++j) acc[j] += w * (float)mv[j];
            }
            #pragma unroll
            for (int off = 32; off > 0; off >>= 1) {
                #pragma unroll
                for (int j = 0; j < 8; ++j) acc[j] += __shfl_down(acc[j], off, 64);
            }
            if (lane == 0) {
                #pragma unroll
                for (int j = 0; j < 4; ++j) {
                    union { unsigned u; _Float16 h[2]; } pk;
                    pk.h[0] = (_Float16)acc[2 * j];
                    pk.h[1] = (_Float16)acc[2 * j + 1];
                    st_agent_u32((unsigned*)(ctx_cur + abt * ENCD + d8 + 2 * j), pk.u);
                }
            }
        }
        if (t > 0) {
            // outproj for step t-1: row n = blk; two 6-chunk batches
            const int b_o = tid & 31;
            const int ks  = tid >> 5;
            const half_t* wrow = Wo + (size_t)blk * (DRNN + ENCD) + ks * 96;
            float outacc = 0.f;
            #pragma unroll
            for (int half = 0; half < 2; ++half) {
                f16x8 wv[6], av[6];
                #pragma unroll
                for (int c8 = 0; c8 < 6; ++c8) {
                    const int cc = half * 6 + c8;
                    const int k = ks * 96 + cc * 8;
                    wv[c8] = *(const f16x8*)(wrow + cc * 8);   // plain, L2-hot
                    const half_t* ap = (k < DRNN) ? (dh_s + b_o * DRNN + k)
                                                  : (ctx_prv + b_o * ENCD + (k - DRNN));
                    av[c8] = ld_agent_f16x8(ap);
                }
                #pragma unroll
                for (int c8 = 0; c8 < 6; ++c8)
                    #pragma unroll
                    for (int e = 0; e < 8; ++e)
                        outacc += (float)wv[c8][e] * (float)av[c8][e];
            }
            lred[ks][b_o] = outacc;
            __syncthreads();
            if (tid < 32) {
                float s = 0.f;
                #pragma unroll
                for (int q = 0; q < 16; ++q) s += lred[q][tid];
                st_agent_f32(&logits[(size_t)tid * Tsteps * NSYM + (size_t)(t - 1) * NSYM + blk],
                             s + ob[blk]);
            }
        }
        if (t < Tsteps) {
            ++ph; g_arrive(flags, ph);
            // ---- cross-barrier prefetch for next iteration's phase1 ----
            // aLSTM_{t+1} B-frags: xpre_{t+1} (plain) + ah_t (sc1); ctx_t deferred
            if (t + 1 < Tsteps) {
                const half_t* s0n = xpre + (size_t)(t + 1) * Bsz * PRE;
                #pragma unroll
                for (int i = 0; i < NMA; ++i) {
                    const int kg = kq * KAQ + i * 32 + (kh << 3);
                    if (kg < PRE)
                        bvA[i] = *(const f16x8*)(s0n + bb * PRE + kg);
                    else if (kg >= PRE + ENCD)
                        bvA[i] = ld_agent_f16x8(ah_cur + bb * ARNN + (kg - PRE - ENCD));
                }
            }
            // dLSTM_t B-frags: ah_t + dh_{t-1} (sc1); ctx_t deferred
            #pragma unroll
            for (int i = 0; i < NMD; ++i) {
                const int kg = kq * KDQ + i * 32 + (kh << 3);
                if (kg < ARNN)
                    bvD[i] = ld_agent_f16x8(ah_cur + bb * ARNN + kg);
                else if (kg >= ARNN + ENCD)
                    bvD[i] = ld_agent_f16x8(dh_s + bb * DRNN + (kg - ARNN - ENCD));
            }
            g_wait(flags, ph);
            // ---- post-wait: ctx_t segments (the only ph2-produced data) ----
            if (t + 1 < Tsteps) {
                #pragma unroll
                for (int i = 0; i < NMA; ++i) {
                    const int kg = kq * KAQ + i * 32 + (kh << 3);
                    if (kg >= PRE && kg < PRE + ENCD)
                        bvA[i] = ld_agent_f16x8(ctx_cur + bb * ENCD + (kg - PRE));
                }
            }
            #pragma unroll
            for (int i = 0; i < NMD; ++i) {
                const int kg = kq * KDQ + i * 32 + (kh << 3);
                if (kg >= ARNN && kg < ARNN + ENCD)
                    bvD[i] = ld_agent_f16x8(ctx_cur + bb * ENCD + (kg - ARNN));
            }
        }
    }
}

// ---------------------------------------------------------------------------
extern "C" void kernel_launch(void* const* d_in, const int* in_sizes, int n_in,
                              void* d_out, int out_size, void* d_ws, size_t ws_size,
                              hipStream_t stream)
{
    (void)in_sizes; (void)n_in; (void)out_size; (void)ws_size;
    const float* memory = (const float*)d_in[0];
    const float* din    = (const float*)d_in[1];
    const int*   mlen   = (const int*)d_in[2];
    const float* pW1    = (const float*)d_in[3];
    const float* pb1    = (const float*)d_in[4];
    const float* pW2    = (const float*)d_in[5];
    const float* pb2    = (const float*)d_in[6];
    const float* aWih   = (const float*)d_in[7];
    const float* aWhh   = (const float*)d_in[8];
    const float* abih   = (const float*)d_in[9];
    const float* abhh   = (const float*)d_in[10];
    const float* attWp  = (const float*)d_in[11];
    const float* attbp  = (const float*)d_in[12];
    const float* dWih   = (const float*)d_in[13];
    const float* dWhh   = (const float*)d_in[14];
    const float* dbih   = (const float*)d_in[15];
    const float* dbhh   = (const float*)d_in[16];
    const float* oW     = (const float*)d_in[17];
    const float* ob     = (const float*)d_in[18];

    float* logits = (float*)d_out;
    float* aligns = logits + (size_t)Bsz * Tsteps * NSYM;
    float* ps     = aligns + (size_t)Bsz * Tsteps * Lmem;

    char* base = (char*)d_ws;
    auto alloc = [&](size_t bytes) -> char* {
        char* p = base; base += (bytes + 255) & ~(size_t)255; return p;
    };
    half_t* Wcat_a = (half_t*)alloc((size_t)4096 * KA * 2);
    half_t* Wcat_d = (half_t*)alloc((size_t)4096 * KD * 2);
    half_t* Wo     = (half_t*)alloc((size_t)NSYM * (DRNN + ENCD) * 2);
    float*  bsum_a = (float*)alloc(4096 * 4);
    float*  bsum_d = (float*)alloc(4096 * 4);
    half_t* xpre   = (half_t*)alloc((size_t)Tsteps * Bsz * PRE * 2);
    half_t* mem16  = (half_t*)alloc((size_t)Bsz * Lmem * ENCD * 2);
    half_t* ah0    = (half_t*)alloc(Bsz * ARNN * 2);
    half_t* ah1    = (half_t*)alloc(Bsz * ARNN * 2);
    half_t* dh0    = (half_t*)alloc(Bsz * DRNN * 2);
    half_t* dh1    = (half_t*)alloc(Bsz * DRNN * 2);
    half_t* ctx0   = (half_t*)alloc(Bsz * ENCD * 2);
    half_t* ctx1   = (half_t*)alloc(Bsz * ENCD * 2);
    float*  mean0  = (float*)alloc(Bsz * 4);
    float*  mean1  = (float*)alloc(Bsz * 4);
    unsigned* flags = (unsigned*)alloc(256 * 16 * 4);

    (void)hipMemsetAsync(ah1,   0, Bsz * ARNN * 2, stream);
    (void)hipMemsetAsync(dh1,   0, Bsz * DRNN * 2, stream);
    (void)hipMemsetAsync(ctx1,  0, Bsz * ENCD * 2, stream);
    (void)hipMemsetAsync(mean0, 0, Bsz * 4, stream);
    (void)hipMemsetAsync(mean1, 0, Bsz * 4, stream);
    (void)hipMemsetAsync(flags, 0, 256 * 16 * 4, stream);

    conv_lstm_w<PRE + ENCD, ARNN><<<4096, 256, 0, stream>>>(
        aWih, aWhh, abih, abhh, Wcat_a, bsum_a);
    conv_lstm_w<ARNN + ENCD, DRNN><<<4096, 256, 0, stream>>>(
        dWih, dWhh, dbih, dbhh, Wcat_d, bsum_d);
    conv_mat<<<768, 256, 0, stream>>>(oW, Wo, NSYM * (DRNN + ENCD));
    conv_mat<<<4096, 256, 0, stream>>>(memory, mem16, Bsz * Lmem * ENCD);
    prenet_kernel<<<Tsteps * Bsz / 8, 256, 0, stream>>>(din, pW1, pb1, pW2, pb2, xpre);

    decoder_persistent<<<256, 512, 0, stream>>>(
        Wcat_a, bsum_a, Wcat_d, bsum_d, Wo, ob, xpre,
        attWp, attbp, mlen, mem16,
        ah0, ah1, dh0, dh1, ctx0, ctx1, mean0, mean1,
        logits, aligns, ps,
        flags);
}